// Round 2
// baseline (1050.235 us; speedup 1.0000x reference)
//
#include <hip/hip_runtime.h>
#include <math.h>

typedef unsigned short bf16_t;

#define LSEQ 4096
#define NTOK 32768
#define HALF_TOK 16384

__device__ __forceinline__ float bf2f(bf16_t u) {
    unsigned int x = ((unsigned int)u) << 16;
    return __uint_as_float(x);
}
__device__ __forceinline__ bf16_t f2bf(float f) {
    unsigned int x = __float_as_uint(f);
    unsigned int r = (x + 0x7FFFu + ((x >> 16) & 1u)) >> 16;
    return (bf16_t)r;
}
__device__ __forceinline__ float siluf(float x) { return x / (1.f + __expf(-x)); }

__device__ __forceinline__ float4 ld4(const float* p) { return *(const float4*)p; }
__device__ __forceinline__ float4 ld4(const bf16_t* p) {
    ushort4 u = *(const ushort4*)p;
    return make_float4(bf2f(u.x), bf2f(u.y), bf2f(u.z), bf2f(u.w));
}
__device__ __forceinline__ void st4(float* p, const float* o) {
    *(float4*)p = make_float4(o[0], o[1], o[2], o[3]);
}
__device__ __forceinline__ void st4(bf16_t* p, const float* o) {
    ushort4 u; u.x = f2bf(o[0]); u.y = f2bf(o[1]); u.z = f2bf(o[2]); u.w = f2bf(o[3]);
    *(ushort4*)p = u;
}
__device__ __forceinline__ void st1(float* p, float v) { *p = v; }
__device__ __forceinline__ void st1(bf16_t* p, float v) { *p = f2bf(v); }

__device__ __forceinline__ void unpack8(uint4 u, float* f) {
    f[0] = bf2f((bf16_t)(u.x & 0xffff)); f[1] = bf2f((bf16_t)(u.x >> 16));
    f[2] = bf2f((bf16_t)(u.y & 0xffff)); f[3] = bf2f((bf16_t)(u.y >> 16));
    f[4] = bf2f((bf16_t)(u.z & 0xffff)); f[5] = bf2f((bf16_t)(u.z >> 16));
    f[6] = bf2f((bf16_t)(u.w & 0xffff)); f[7] = bf2f((bf16_t)(u.w >> 16));
}
__device__ __forceinline__ uint4 pack8(const float* f) {
    uint4 u;
    u.x = (unsigned)f2bf(f[0]) | ((unsigned)f2bf(f[1]) << 16);
    u.y = (unsigned)f2bf(f[2]) | ((unsigned)f2bf(f[3]) << 16);
    u.z = (unsigned)f2bf(f[4]) | ((unsigned)f2bf(f[5]) << 16);
    u.w = (unsigned)f2bf(f[6]) | ((unsigned)f2bf(f[7]) << 16);
    return u;
}

// ---------------- LayerNorm over concat(x0,x1), row=token (256 feats) ----------------
__global__ __launch_bounds__(256) void ln_cat_kernel(
    const float* __restrict__ x0, const float* __restrict__ x1,
    const float* __restrict__ w, const float* __restrict__ b,
    float* __restrict__ out)
{
    int row = blockIdx.x * 4 + (threadIdx.x >> 6);
    int lane = threadIdx.x & 63;
    const float* src = (row < HALF_TOK) ? x0 + (size_t)row * 256
                                        : x1 + (size_t)(row - HALF_TOK) * 256;
    float4 v = ((const float4*)src)[lane];
    float s = v.x + v.y + v.z + v.w;
    float sq = v.x*v.x + v.y*v.y + v.z*v.z + v.w*v.w;
    #pragma unroll
    for (int off = 32; off; off >>= 1) { s += __shfl_xor(s, off); sq += __shfl_xor(sq, off); }
    float mu = s * (1.f/256.f);
    float var = sq * (1.f/256.f) - mu*mu;
    float inv = rsqrtf(var + 1e-5f);
    float4 wv = ((const float4*)w)[lane];
    float4 bv = ((const float4*)b)[lane];
    float4 o;
    o.x = (v.x-mu)*inv*wv.x + bv.x;
    o.y = (v.y-mu)*inv*wv.y + bv.y;
    o.z = (v.z-mu)*inv*wv.z + bv.z;
    o.w = (v.w-mu)*inv*wv.w + bv.w;
    ((float4*)(out + (size_t)row * 256))[lane] = o;
}

// ---------------- Generic C = A(MxK) @ W(NxK)^T, 64x64 tile ----------------
template<typename TA, typename TC, bool BIAS, bool SILU>
__global__ __launch_bounds__(256) void gemm_bt(
    const TA* __restrict__ A, const float* __restrict__ W,
    const float* __restrict__ bias, TC* __restrict__ C,
    int M, int N, int K)
{
    __shared__ float As[16][68];
    __shared__ float Ws[16][68];
    int tid = threadIdx.x;
    int tx = tid & 15, ty = tid >> 4;
    int m0 = blockIdx.x << 6, n0 = blockIdx.y << 6;
    int lr = tid >> 2, lq = (tid & 3) << 2;
    float acc[4][4] = {};
    const TA* Aptr = A + (size_t)(m0 + lr) * K + lq;
    const float* Wptr = (n0 + lr < N) ? (W + (size_t)(n0 + lr) * K + lq) : nullptr;
    for (int k0 = 0; k0 < K; k0 += 16) {
        float4 av = ld4(Aptr + k0);
        float4 wv = make_float4(0.f, 0.f, 0.f, 0.f);
        if (Wptr) wv = *(const float4*)(Wptr + k0);
        __syncthreads();
        As[lq+0][lr] = av.x; As[lq+1][lr] = av.y; As[lq+2][lr] = av.z; As[lq+3][lr] = av.w;
        Ws[lq+0][lr] = wv.x; Ws[lq+1][lr] = wv.y; Ws[lq+2][lr] = wv.z; Ws[lq+3][lr] = wv.w;
        __syncthreads();
        #pragma unroll
        for (int k = 0; k < 16; ++k) {
            float a[4], bb[4];
            *(float4*)a  = *(const float4*)&As[k][ty << 2];
            *(float4*)bb = *(const float4*)&Ws[k][tx << 2];
            #pragma unroll
            for (int i = 0; i < 4; ++i)
                #pragma unroll
                for (int j = 0; j < 4; ++j)
                    acc[i][j] += a[i] * bb[j];
        }
    }
    #pragma unroll
    for (int i = 0; i < 4; ++i) {
        int m = m0 + (ty << 2) + i;
        int n = n0 + (tx << 2);
        size_t crow = (size_t)m * N;
        float o[4];
        #pragma unroll
        for (int j = 0; j < 4; ++j) o[j] = acc[i][j];
        if (n + 3 < N) {
            if (BIAS) { o[0]+=bias[n]; o[1]+=bias[n+1]; o[2]+=bias[n+2]; o[3]+=bias[n+3]; }
            if (SILU) { o[0]=siluf(o[0]); o[1]=siluf(o[1]); o[2]=siluf(o[2]); o[3]=siluf(o[3]); }
            st4(C + crow + n, o);
        } else {
            #pragma unroll
            for (int j = 0; j < 4; ++j) {
                if (n + j < N) {
                    float v = o[j];
                    if (BIAS) v += bias[n + j];
                    if (SILU) v = siluf(v);
                    st1(C + crow + n + j, v);
                }
            }
        }
    }
}

// ---------------- causal conv (width 4) + SiLU; also dt=softplus, log(dA) ----------------
__global__ __launch_bounds__(256) void conv_dt_kernel(
    const bf16_t* __restrict__ zx, const float* __restrict__ cw,
    const float* __restrict__ cb, const float* __restrict__ dtb,
    const float* __restrict__ alog,
    bf16_t* __restrict__ conv_out, float* __restrict__ dts, float* __restrict__ lda)
{
    int tok = blockIdx.x;
    int b = tok >> 12, t = tok & 4095;
    for (int ch = threadIdx.x; ch < 640; ch += 256) {
        float acc = cb[ch];
        #pragma unroll
        for (int k = 0; k < 4; ++k) {
            int tp = t - 3 + k;
            if (tp >= 0)
                acc += bf2f(zx[(size_t)(b * LSEQ + tp) * 1160 + 512 + ch]) * cw[ch * 4 + k];
        }
        conv_out[(size_t)tok * 640 + ch] = f2bf(siluf(acc));
    }
    if (threadIdx.x < 8) {
        int h = threadIdx.x;
        float raw = bf2f(zx[(size_t)tok * 1160 + 1152 + h]) + dtb[h];
        float dt = (raw > 20.f) ? raw : log1pf(__expf(raw));
        dts[tok * 8 + h] = dt;
        lda[tok * 8 + h] = -dt * __expf(alog[h]);
    }
}

// ---------------- scan pass A: per-chunk local end state ----------------
__global__ __launch_bounds__(256) void scan_passA(
    const bf16_t* __restrict__ conv_out, const float* __restrict__ dts,
    const float* __restrict__ lda, bf16_t* __restrict__ SH, float* __restrict__ Dtot)
{
    int bh = blockIdx.x, c = blockIdx.y;
    int b = bh >> 3, h = bh & 7;
    __shared__ float Xs[64][65];
    __shared__ float Bls[64][65];
    __shared__ float wls[64];
    int tid = threadIdx.x;
    int tokbase = b * LSEQ + c * 64;
    if (tid < 64) {
        float la = lda[(tokbase + tid) * 8 + h];
        #pragma unroll
        for (int off = 1; off < 64; off <<= 1) {
            float up = __shfl_up(la, off);
            if (tid >= off) la += up;
        }
        float tot = __shfl(la, 63);
        wls[tid] = __expf(tot - la) * dts[(tokbase + tid) * 8 + h];
        if (tid == 63) Dtot[bh * 64 + c] = __expf(tot);
    }
    __syncthreads();
    int ln = tid & 63, ls4 = tid >> 6;
    for (int it = 0; it < 16; ++it) {
        int s = ls4 + 4 * it;
        size_t rb = (size_t)(tokbase + s) * 640;
        Xs[s][ln]  = bf2f(conv_out[rb + h * 64 + ln]) * wls[s];
        Bls[s][ln] = bf2f(conv_out[rb + 512 + ln]);
    }
    __syncthreads();
    int tx = tid & 15, ty = tid >> 4;
    float acc[4][4] = {};
    for (int s = 0; s < 64; ++s) {
        float xv[4], bv[4];
        #pragma unroll
        for (int i = 0; i < 4; ++i) xv[i] = Xs[s][(ty << 2) + i];
        #pragma unroll
        for (int j = 0; j < 4; ++j) bv[j] = Bls[s][(tx << 2) + j];
        #pragma unroll
        for (int i = 0; i < 4; ++i)
            #pragma unroll
            for (int j = 0; j < 4; ++j)
                acc[i][j] += xv[i] * bv[j];
    }
    size_t base = (size_t)(bh * 64 + c) * 4096;
    #pragma unroll
    for (int i = 0; i < 4; ++i)
        st4(SH + base + ((ty << 2) + i) * 64 + (tx << 2), acc[i]);
}

// ---------------- scan pass B: inter-chunk recurrence (SH[c] -> state at chunk START) ----------------
__global__ __launch_bounds__(256) void scan_passB(bf16_t* __restrict__ SH, const float* __restrict__ Dtot)
{
    int bh = blockIdx.x;
    int elem = blockIdx.y * 256 + threadIdx.x;   // 0..4095
    size_t base = (size_t)bh * 64 * 4096 + elem;
    float H = 0.f;
    for (int c = 0; c < 64; ++c) {
        float d = Dtot[bh * 64 + c];
        size_t a = base + (size_t)c * 4096;
        float s = bf2f(SH[a]);
        SH[a] = f2bf(H);
        H = d * H + s;
    }
}

// ---------------- scan pass C: outputs ----------------
__global__ __launch_bounds__(256) void scan_passC(
    const bf16_t* __restrict__ conv_out, const float* __restrict__ dts,
    const float* __restrict__ lda, const bf16_t* __restrict__ SH,
    bf16_t* __restrict__ ybuf)
{
    int bh = blockIdx.x, c = blockIdx.y;
    int b = bh >> 3, h = bh & 7;
    __shared__ float Cs[64][65];
    __shared__ float U1[64][65];   // B, then M1
    __shared__ float U2[64][65];   // H, then X
    __shared__ float La_sh[64], dt_sh[64], ce_sh[64];
    int tid = threadIdx.x;
    int tokbase = b * LSEQ + c * 64;
    if (tid < 64) {
        float la = lda[(tokbase + tid) * 8 + h];
        #pragma unroll
        for (int off = 1; off < 64; off <<= 1) {
            float up = __shfl_up(la, off);
            if (tid >= off) la += up;
        }
        La_sh[tid] = la;
        ce_sh[tid] = __expf(la);
        dt_sh[tid] = dts[(tokbase + tid) * 8 + h];
    }
    int ln = tid & 63, ls4 = tid >> 6;
    size_t shbase = (size_t)(bh * 64 + c) * 4096;
    for (int it = 0; it < 16; ++it) {
        int r = ls4 + 4 * it;
        size_t rb = (size_t)(tokbase + r) * 640;
        Cs[r][ln] = bf2f(conv_out[rb + 576 + ln]);
        U1[r][ln] = bf2f(conv_out[rb + 512 + ln]);
        U2[r][ln] = bf2f(SH[shbase + r * 64 + ln]);   // H[p][n]
    }
    __syncthreads();
    int tx = tid & 15, ty = tid >> 4;
    float G[4][4] = {}, CH[4][4] = {};
    for (int n = 0; n < 64; ++n) {
        float cv[4], bv[4], hv[4];
        #pragma unroll
        for (int i = 0; i < 4; ++i) cv[i] = Cs[(ty << 2) + i][n];
        #pragma unroll
        for (int j = 0; j < 4; ++j) { bv[j] = U1[(tx << 2) + j][n]; hv[j] = U2[(tx << 2) + j][n]; }
        #pragma unroll
        for (int i = 0; i < 4; ++i)
            #pragma unroll
            for (int j = 0; j < 4; ++j) {
                G[i][j]  += cv[i] * bv[j];
                CH[i][j] += cv[i] * hv[j];
            }
    }
    __syncthreads();
    #pragma unroll
    for (int i = 0; i < 4; ++i)
        #pragma unroll
        for (int j = 0; j < 4; ++j) {
            int s = (ty << 2) + i, r = (tx << 2) + j;
            float m = 0.f;
            if (r <= s) m = G[i][j] * __expf(La_sh[s] - La_sh[r]) * dt_sh[r];
            U1[s][r] = m;
        }
    for (int it = 0; it < 16; ++it) {
        int r = ls4 + 4 * it;
        U2[r][ln] = bf2f(conv_out[(size_t)(tokbase + r) * 640 + h * 64 + ln]);
    }
    __syncthreads();
    float Y[4][4];
    #pragma unroll
    for (int i = 0; i < 4; ++i)
        #pragma unroll
        for (int j = 0; j < 4; ++j)
            Y[i][j] = ce_sh[(ty << 2) + i] * CH[i][j];
    for (int r = 0; r < 64; ++r) {
        float mv[4], xv[4];
        #pragma unroll
        for (int i = 0; i < 4; ++i) mv[i] = U1[(ty << 2) + i][r];
        #pragma unroll
        for (int j = 0; j < 4; ++j) xv[j] = U2[r][(tx << 2) + j];
        #pragma unroll
        for (int i = 0; i < 4; ++i)
            #pragma unroll
            for (int j = 0; j < 4; ++j)
                Y[i][j] += mv[i] * xv[j];
    }
    #pragma unroll
    for (int i = 0; i < 4; ++i) {
        int s = (ty << 2) + i;
        st4(ybuf + (size_t)(tokbase + s) * 512 + h * 64 + (tx << 2), Y[i]);
    }
}

// ---------------- gate: y=(y+D*xh)*silu(z), then RMSNorm(512)*rms_w, in-place ----------------
__global__ __launch_bounds__(256) void gate_rms_kernel(
    bf16_t* __restrict__ y, const bf16_t* __restrict__ conv_out,
    const bf16_t* __restrict__ zx, const float* __restrict__ Dp,
    const float* __restrict__ rw)
{
    int row = blockIdx.x * 4 + (threadIdx.x >> 6);
    int lane = threadIdx.x & 63;
    uint4* yrow = (uint4*)(y + (size_t)row * 512);
    uint4 uy = yrow[lane];
    uint4 ux = *(const uint4*)(conv_out + (size_t)row * 640 + lane * 8);
    uint4 uz = *(const uint4*)(zx + (size_t)row * 1160 + lane * 8);
    float fy[8], fx[8], fz[8];
    unpack8(uy, fy); unpack8(ux, fx); unpack8(uz, fz);
    float d = Dp[lane >> 3];
    float v[8];
    float sq = 0.f;
    #pragma unroll
    for (int i = 0; i < 8; ++i) {
        v[i] = (fy[i] + d * fx[i]) * siluf(fz[i]);
        sq += v[i] * v[i];
    }
    #pragma unroll
    for (int off = 32; off; off >>= 1) sq += __shfl_xor(sq, off);
    float r = rsqrtf(sq * (1.f/512.f) + 1e-5f);
    float4 w0 = *(const float4*)(rw + lane * 8);
    float4 w1 = *(const float4*)(rw + lane * 8 + 4);
    float o[8];
    o[0] = v[0]*r*w0.x; o[1] = v[1]*r*w0.y; o[2] = v[2]*r*w0.z; o[3] = v[3]*r*w0.w;
    o[4] = v[4]*r*w1.x; o[5] = v[5]*r*w1.y; o[6] = v[6]*r*w1.z; o[7] = v[7]*r*w1.w;
    yrow[lane] = pack8(o);
}

// ---------------- sp += concat(x0,x1) residual ----------------
__global__ __launch_bounds__(256) void add_res_kernel(
    float4* __restrict__ sp, const float4* __restrict__ x0, const float4* __restrict__ x1)
{
    const int half = HALF_TOK * 64;
    for (int i = blockIdx.x * 256 + threadIdx.x; i < 2 * half; i += 2048 * 256) {
        float4 r = (i < half) ? x0[i] : x1[i - half];
        float4 v = sp[i];
        v.x += r.x; v.y += r.y; v.z += r.z; v.w += r.w;
        sp[i] = v;
    }
}

// ---------------- Xcat[m] = [sp[m] | sp[m ^ 16384]] ----------------
__global__ __launch_bounds__(256) void build_xcat_kernel(
    const float4* __restrict__ sp, float4* __restrict__ xcat)
{
    for (int i = blockIdx.x * 256 + threadIdx.x; i < NTOK * 128; i += 4096 * 256) {
        int m = i >> 7, q = i & 127;
        float4 v = (q < 64) ? sp[m * 64 + q] : sp[(m ^ HALF_TOK) * 64 + (q - 64)];
        xcat[i] = v;
    }
}

// ---------------- final: out = LN(sp + m_out) ----------------
__global__ __launch_bounds__(256) void final_ln_kernel(
    const float* __restrict__ sp, const float* __restrict__ mo,
    const float* __restrict__ w, const float* __restrict__ b,
    float* __restrict__ out)
{
    int row = blockIdx.x * 4 + (threadIdx.x >> 6);
    int lane = threadIdx.x & 63;
    float4 a = ((const float4*)(sp + (size_t)row * 256))[lane];
    float4 c = ((const float4*)(mo + (size_t)row * 256))[lane];
    float4 v = {a.x + c.x, a.y + c.y, a.z + c.z, a.w + c.w};
    float s = v.x + v.y + v.z + v.w;
    float sq = v.x*v.x + v.y*v.y + v.z*v.z + v.w*v.w;
    #pragma unroll
    for (int off = 32; off; off >>= 1) { s += __shfl_xor(s, off); sq += __shfl_xor(sq, off); }
    float mu = s * (1.f/256.f);
    float var = sq * (1.f/256.f) - mu*mu;
    float inv = rsqrtf(var + 1e-5f);
    float4 wv = ((const float4*)w)[lane];
    float4 bv = ((const float4*)b)[lane];
    float4 o;
    o.x = (v.x-mu)*inv*wv.x + bv.x;
    o.y = (v.y-mu)*inv*wv.y + bv.y;
    o.z = (v.z-mu)*inv*wv.z + bv.z;
    o.w = (v.w-mu)*inv*wv.w + bv.w;
    ((float4*)(out + (size_t)row * 256))[lane] = o;
}

extern "C" void kernel_launch(void* const* d_in, const int* in_sizes, int n_in,
                              void* d_out, int out_size, void* d_ws, size_t ws_size,
                              hipStream_t stream) {
    (void)in_sizes; (void)n_in; (void)out_size; (void)ws_size;
    const float* x0      = (const float*)d_in[0];
    const float* x1      = (const float*)d_in[1];
    const float* nsw     = (const float*)d_in[2];
    const float* nsb     = (const float*)d_in[3];
    const float* W_in    = (const float*)d_in[4];
    const float* conv_w  = (const float*)d_in[5];
    const float* conv_b  = (const float*)d_in[6];
    const float* dt_bias = (const float*)d_in[7];
    const float* A_log   = (const float*)d_in[8];
    const float* D_param = (const float*)d_in[9];
    const float* rms_w   = (const float*)d_in[10];
    const float* W_out   = (const float*)d_in[11];
    const float* mlp_w1  = (const float*)d_in[12];
    const float* mlp_b1  = (const float*)d_in[13];
    const float* mlp_w2  = (const float*)d_in[14];
    const float* mlp_b2  = (const float*)d_in[15];
    const float* ntw     = (const float*)d_in[16];
    const float* ntb     = (const float*)d_in[17];
    float* out = (float*)d_out;

    // ---- workspace layout (bytes), total 187,187,200 B ----
    char* base = (char*)d_ws;
    // RA [0, 76,021,760): zx bf16 (32768x1160); later xcat f32 (32768x512 = 67,108,864 B)
    bf16_t* zx   = (bf16_t*)base;
    float*  xcat = (float*)base;
    char* pB = base + 76021760;
    // RB 41,943,040 B: convo bf16 (32768x640); later sp f32 (32768x256 = 33,554,432 B)
    bf16_t* convo = (bf16_t*)pB;
    float*  sp    = (float*)pB;
    char* pC = pB + 41943040;
    // RC 33,554,432 B: x_norm f32 (32768x256); later SH bf16 (64x64x4096); later hbuf f32 (32768x256)
    float*  x_norm = (float*)pC;
    bf16_t* SH     = (bf16_t*)pC;
    float*  hbuf   = (float*)pC;
    char* pD = pC + 33554432;
    // RD 33,554,432 B: ybuf bf16 (32768x512); later mout f32 (32768x256)
    bf16_t* ybuf = (bf16_t*)pD;
    float*  mout = (float*)pD;
    char* pE = pD + 33554432;
    float* dts  = (float*)pE;          // 262,144 f32
    float* lda  = dts + 262144;        // 262,144 f32
    float* dtot = lda + 262144;        // 4,096 f32

    ln_cat_kernel<<<8192, 256, 0, stream>>>(x0, x1, nsw, nsb, x_norm);

    dim3 g_in(512, 19);
    gemm_bt<float, bf16_t, false, false><<<g_in, 256, 0, stream>>>(x_norm, W_in, nullptr, zx, NTOK, 1160, 256);

    conv_dt_kernel<<<NTOK, 256, 0, stream>>>(zx, conv_w, conv_b, dt_bias, A_log, convo, dts, lda);

    dim3 g_scan(64, 64);
    scan_passA<<<g_scan, 256, 0, stream>>>(convo, dts, lda, SH, dtot);
    dim3 g_pb(64, 16);
    scan_passB<<<g_pb, 256, 0, stream>>>(SH, dtot);
    scan_passC<<<g_scan, 256, 0, stream>>>(convo, dts, lda, SH, ybuf);

    gate_rms_kernel<<<8192, 256, 0, stream>>>(ybuf, convo, zx, D_param, rms_w);

    dim3 g_out(512, 4);
    gemm_bt<bf16_t, float, false, false><<<g_out, 256, 0, stream>>>(ybuf, W_out, nullptr, sp, NTOK, 256, 512);

    add_res_kernel<<<2048, 256, 0, stream>>>((float4*)sp, (const float4*)x0, (const float4*)x1);
    build_xcat_kernel<<<4096, 256, 0, stream>>>((const float4*)sp, (float4*)xcat);

    gemm_bt<float, float, true, true ><<<g_out, 256, 0, stream>>>(xcat, mlp_w1, mlp_b1, hbuf, NTOK, 256, 512);
    gemm_bt<float, float, true, false><<<g_out, 256, 0, stream>>>(hbuf, mlp_w2, mlp_b2, mout, NTOK, 256, 256);

    final_ln_kernel<<<8192, 256, 0, stream>>>(sp, mout, ntw, ntb, out);
}

// Round 3
// 578.705 us; speedup vs baseline: 1.8148x; 1.8148x over previous
//
#include <hip/hip_runtime.h>
#include <math.h>

typedef unsigned short bf16_t;
typedef __attribute__((ext_vector_type(8))) short bf16x8;
typedef __attribute__((ext_vector_type(4))) float f32x4;

#define LSEQ 4096
#define NTOK 32768
#define HALF_TOK 16384

__device__ __forceinline__ float bf2f(bf16_t u) {
    unsigned int x = ((unsigned int)u) << 16;
    return __uint_as_float(x);
}
__device__ __forceinline__ bf16_t f2bf(float f) {
    unsigned int x = __float_as_uint(f);
    unsigned int r = (x + 0x7FFFu + ((x >> 16) & 1u)) >> 16;
    return (bf16_t)r;
}
__device__ __forceinline__ float siluf(float x) { return x / (1.f + __expf(-x)); }

__device__ __forceinline__ void unpack8(uint4 u, float* f) {
    f[0] = bf2f((bf16_t)(u.x & 0xffff)); f[1] = bf2f((bf16_t)(u.x >> 16));
    f[2] = bf2f((bf16_t)(u.y & 0xffff)); f[3] = bf2f((bf16_t)(u.y >> 16));
    f[4] = bf2f((bf16_t)(u.z & 0xffff)); f[5] = bf2f((bf16_t)(u.z >> 16));
    f[6] = bf2f((bf16_t)(u.w & 0xffff)); f[7] = bf2f((bf16_t)(u.w >> 16));
}
__device__ __forceinline__ uint4 pack8(const float* f) {
    uint4 u;
    u.x = (unsigned)f2bf(f[0]) | ((unsigned)f2bf(f[1]) << 16);
    u.y = (unsigned)f2bf(f[2]) | ((unsigned)f2bf(f[3]) << 16);
    u.z = (unsigned)f2bf(f[4]) | ((unsigned)f2bf(f[5]) << 16);
    u.w = (unsigned)f2bf(f[6]) | ((unsigned)f2bf(f[7]) << 16);
    return u;
}
__device__ __forceinline__ void st4(float* p, const float* o) {
    *(float4*)p = make_float4(o[0], o[1], o[2], o[3]);
}
__device__ __forceinline__ void st4(bf16_t* p, const float* o) {
    ushort4 u; u.x = f2bf(o[0]); u.y = f2bf(o[1]); u.z = f2bf(o[2]); u.w = f2bf(o[3]);
    *(ushort4*)p = u;
}

// ---------------- weight f32 -> bf16 ----------------
__global__ __launch_bounds__(256) void wconv_kernel(
    const float* __restrict__ s, bf16_t* __restrict__ d, int n4)
{
    int i = blockIdx.x * 256 + threadIdx.x;
    if (i < n4) {
        float4 v = ((const float4*)s)[i];
        ushort4 u; u.x = f2bf(v.x); u.y = f2bf(v.y); u.z = f2bf(v.z); u.w = f2bf(v.w);
        ((ushort4*)d)[i] = u;
    }
}

// ---------------- LayerNorm over concat(x0,x1) -> bf16 ----------------
__global__ __launch_bounds__(256) void ln_cat_kernel(
    const float* __restrict__ x0, const float* __restrict__ x1,
    const float* __restrict__ w, const float* __restrict__ b,
    bf16_t* __restrict__ out)
{
    int row = blockIdx.x * 4 + (threadIdx.x >> 6);
    int lane = threadIdx.x & 63;
    const float* src = (row < HALF_TOK) ? x0 + (size_t)row * 256
                                        : x1 + (size_t)(row - HALF_TOK) * 256;
    float4 v = ((const float4*)src)[lane];
    float s = v.x + v.y + v.z + v.w;
    float sq = v.x*v.x + v.y*v.y + v.z*v.z + v.w*v.w;
    #pragma unroll
    for (int off = 32; off; off >>= 1) { s += __shfl_xor(s, off); sq += __shfl_xor(sq, off); }
    float mu = s * (1.f/256.f);
    float var = sq * (1.f/256.f) - mu*mu;
    float inv = rsqrtf(var + 1e-5f);
    float4 wv = ((const float4*)w)[lane];
    float4 bv = ((const float4*)b)[lane];
    float o[4];
    o[0] = (v.x-mu)*inv*wv.x + bv.x;
    o[1] = (v.y-mu)*inv*wv.y + bv.y;
    o[2] = (v.z-mu)*inv*wv.z + bv.z;
    o[3] = (v.w-mu)*inv*wv.w + bv.w;
    st4(out + (size_t)row * 256 + lane * 4, o);
}

// ---------------- MFMA GEMM: C = A(MxK) @ W(NxK)^T ----------------
// AMODE: 0 = A bf16 row-major; 1 = A f32 row-major; 2 = A f32 concat pair
//        (row m: cols [0,256) from A[m], cols [256,512) from A[m^HALF_TOK])
template<int AMODE, typename TC, bool BIAS, bool SILU, bool RES>
__global__ __launch_bounds__(256) void gemm_mfma(
    const void* __restrict__ Avoid, const bf16_t* __restrict__ W,
    const float* __restrict__ bias, TC* __restrict__ C,
    const float* __restrict__ r0, const float* __restrict__ r1,
    int M, int N, int K)
{
    __shared__ bf16_t As[128][40];   // row stride 80 B -> 2-way bank aliasing (free)
    __shared__ bf16_t Ws[128][40];
    int tid = threadIdx.x;
    int m0 = blockIdx.x << 7, n0 = blockIdx.y << 7;
    int wave = tid >> 6, lane = tid & 63;
    int wr = wave >> 1, wc = wave & 1;
    int fr = lane & 15, fk = lane >> 4;

    f32x4 acc[4][4] = {};

    for (int k0 = 0; k0 < K; k0 += 32) {
        __syncthreads();
        #pragma unroll
        for (int ss = 0; ss < 2; ++ss) {
            int s = tid + ss * 256;
            int row = s >> 2, cs = s & 3;
            int kk = k0 + cs * 8;
            // ---- A tile ----
            if (AMODE == 0) {
                const bf16_t* Ap = (const bf16_t*)Avoid;
                uint4 v = *(const uint4*)(Ap + (size_t)(m0 + row) * K + kk);
                *(uint4*)&As[row][cs * 8] = v;
            } else if (AMODE == 1) {
                const float* Ap = (const float*)Avoid;
                const float* p = Ap + (size_t)(m0 + row) * K + kk;
                float4 f0 = *(const float4*)p, f1 = *(const float4*)(p + 4);
                float f[8] = {f0.x, f0.y, f0.z, f0.w, f1.x, f1.y, f1.z, f1.w};
                *(uint4*)&As[row][cs * 8] = pack8(f);
            } else {
                const float* Ap = (const float*)Avoid;
                int m = m0 + row;
                const float* p = (kk < 256) ? (Ap + (size_t)m * 256 + kk)
                                            : (Ap + (size_t)(m ^ HALF_TOK) * 256 + (kk - 256));
                float4 f0 = *(const float4*)p, f1 = *(const float4*)(p + 4);
                float f[8] = {f0.x, f0.y, f0.z, f0.w, f1.x, f1.y, f1.z, f1.w};
                *(uint4*)&As[row][cs * 8] = pack8(f);
            }
            // ---- W tile (guard rows >= N with zeros) ----
            uint4 wv = make_uint4(0u, 0u, 0u, 0u);
            if (n0 + row < N) wv = *(const uint4*)(W + (size_t)(n0 + row) * K + kk);
            *(uint4*)&Ws[row][cs * 8] = wv;
        }
        __syncthreads();

        bf16x8 af[4], bf[4];
        #pragma unroll
        for (int i = 0; i < 4; ++i)
            af[i] = *(const bf16x8*)&As[wr * 64 + i * 16 + fr][fk * 8];
        #pragma unroll
        for (int j = 0; j < 4; ++j)
            bf[j] = *(const bf16x8*)&Ws[wc * 64 + j * 16 + fr][fk * 8];
        #pragma unroll
        for (int i = 0; i < 4; ++i)
            #pragma unroll
            for (int j = 0; j < 4; ++j)
                acc[i][j] = __builtin_amdgcn_mfma_f32_16x16x32_bf16(af[i], bf[j], acc[i][j], 0, 0, 0);
    }

    // epilogue: C[m][n], m = m0+wr*64+i*16+fq*4+q, n = n0+wc*64+j*16+fr
    int fq = lane >> 4;
    #pragma unroll
    for (int j = 0; j < 4; ++j) {
        int n = n0 + wc * 64 + j * 16 + fr;
        if (n >= N) continue;
        float bval = BIAS ? bias[n] : 0.f;
        #pragma unroll
        for (int i = 0; i < 4; ++i) {
            #pragma unroll
            for (int q = 0; q < 4; ++q) {
                int m = m0 + wr * 64 + i * 16 + fq * 4 + q;
                float v = acc[i][j][q];
                if (BIAS) v += bval;
                if (SILU) v = siluf(v);
                if (RES) v += (m < HALF_TOK) ? r0[(size_t)m * 256 + n]
                                             : r1[(size_t)(m - HALF_TOK) * 256 + n];
                if (sizeof(TC) == 4) ((float*)C)[(size_t)m * N + n] = v;
                else ((bf16_t*)C)[(size_t)m * N + n] = f2bf(v);
            }
        }
    }
}

// ---------------- causal conv (width 4) + SiLU; dt=softplus, log(dA) ----------------
__global__ __launch_bounds__(256) void conv_dt_kernel(
    const bf16_t* __restrict__ zx, const float* __restrict__ cw,
    const float* __restrict__ cb, const float* __restrict__ dtb,
    const float* __restrict__ alog,
    bf16_t* __restrict__ conv_out, float* __restrict__ dts, float* __restrict__ lda)
{
    int tok = blockIdx.x;
    int b = tok >> 12, t = tok & 4095;
    for (int ch = threadIdx.x; ch < 640; ch += 256) {
        float acc = cb[ch];
        #pragma unroll
        for (int k = 0; k < 4; ++k) {
            int tp = t - 3 + k;
            if (tp >= 0)
                acc += bf2f(zx[(size_t)(b * LSEQ + tp) * 1160 + 512 + ch]) * cw[ch * 4 + k];
        }
        conv_out[(size_t)tok * 640 + ch] = f2bf(siluf(acc));
    }
    if (threadIdx.x < 8) {
        int h = threadIdx.x;
        float raw = bf2f(zx[(size_t)tok * 1160 + 1152 + h]) + dtb[h];
        float dt = (raw > 20.f) ? raw : log1pf(__expf(raw));
        dts[tok * 8 + h] = dt;
        lda[tok * 8 + h] = -dt * __expf(alog[h]);
    }
}

// ---------------- scan pass A ----------------
__global__ __launch_bounds__(256) void scan_passA(
    const bf16_t* __restrict__ conv_out, const float* __restrict__ dts,
    const float* __restrict__ lda, bf16_t* __restrict__ SH, float* __restrict__ Dtot)
{
    int bh = blockIdx.x, c = blockIdx.y;
    int b = bh >> 3, h = bh & 7;
    __shared__ float Xs[64][65];
    __shared__ float Bls[64][65];
    __shared__ float wls[64];
    int tid = threadIdx.x;
    int tokbase = b * LSEQ + c * 64;
    if (tid < 64) {
        float la = lda[(tokbase + tid) * 8 + h];
        #pragma unroll
        for (int off = 1; off < 64; off <<= 1) {
            float up = __shfl_up(la, off);
            if (tid >= off) la += up;
        }
        float tot = __shfl(la, 63);
        wls[tid] = __expf(tot - la) * dts[(tokbase + tid) * 8 + h];
        if (tid == 63) Dtot[bh * 64 + c] = __expf(tot);
    }
    __syncthreads();
    int ln = tid & 63, ls4 = tid >> 6;
    for (int it = 0; it < 16; ++it) {
        int s = ls4 + 4 * it;
        size_t rb = (size_t)(tokbase + s) * 640;
        Xs[s][ln]  = bf2f(conv_out[rb + h * 64 + ln]) * wls[s];
        Bls[s][ln] = bf2f(conv_out[rb + 512 + ln]);
    }
    __syncthreads();
    int tx = tid & 15, ty = tid >> 4;
    float acc[4][4] = {};
    for (int s = 0; s < 64; ++s) {
        float xv[4], bv[4];
        #pragma unroll
        for (int i = 0; i < 4; ++i) xv[i] = Xs[s][(ty << 2) + i];
        #pragma unroll
        for (int j = 0; j < 4; ++j) bv[j] = Bls[s][(tx << 2) + j];
        #pragma unroll
        for (int i = 0; i < 4; ++i)
            #pragma unroll
            for (int j = 0; j < 4; ++j)
                acc[i][j] += xv[i] * bv[j];
    }
    size_t base = (size_t)(bh * 64 + c) * 4096;
    #pragma unroll
    for (int i = 0; i < 4; ++i)
        st4(SH + base + ((ty << 2) + i) * 64 + (tx << 2), acc[i]);
}

// ---------------- scan pass B ----------------
__global__ __launch_bounds__(256) void scan_passB(bf16_t* __restrict__ SH, const float* __restrict__ Dtot)
{
    int bh = blockIdx.x;
    int elem = blockIdx.y * 256 + threadIdx.x;
    size_t base = (size_t)bh * 64 * 4096 + elem;
    float H = 0.f;
    for (int c = 0; c < 64; ++c) {
        float d = Dtot[bh * 64 + c];
        size_t a = base + (size_t)c * 4096;
        float s = bf2f(SH[a]);
        SH[a] = f2bf(H);
        H = d * H + s;
    }
}

// ---------------- scan pass C ----------------
__global__ __launch_bounds__(256) void scan_passC(
    const bf16_t* __restrict__ conv_out, const float* __restrict__ dts,
    const float* __restrict__ lda, const bf16_t* __restrict__ SH,
    bf16_t* __restrict__ ybuf)
{
    int bh = blockIdx.x, c = blockIdx.y;
    int b = bh >> 3, h = bh & 7;
    __shared__ float Cs[64][65];
    __shared__ float U1[64][65];
    __shared__ float U2[64][65];
    __shared__ float La_sh[64], dt_sh[64], ce_sh[64];
    int tid = threadIdx.x;
    int tokbase = b * LSEQ + c * 64;
    if (tid < 64) {
        float la = lda[(tokbase + tid) * 8 + h];
        #pragma unroll
        for (int off = 1; off < 64; off <<= 1) {
            float up = __shfl_up(la, off);
            if (tid >= off) la += up;
        }
        La_sh[tid] = la;
        ce_sh[tid] = __expf(la);
        dt_sh[tid] = dts[(tokbase + tid) * 8 + h];
    }
    int ln = tid & 63, ls4 = tid >> 6;
    size_t shbase = (size_t)(bh * 64 + c) * 4096;
    for (int it = 0; it < 16; ++it) {
        int r = ls4 + 4 * it;
        size_t rb = (size_t)(tokbase + r) * 640;
        Cs[r][ln] = bf2f(conv_out[rb + 576 + ln]);
        U1[r][ln] = bf2f(conv_out[rb + 512 + ln]);
        U2[r][ln] = bf2f(SH[shbase + r * 64 + ln]);
    }
    __syncthreads();
    int tx = tid & 15, ty = tid >> 4;
    float G[4][4] = {}, CH[4][4] = {};
    for (int n = 0; n < 64; ++n) {
        float cv[4], bv[4], hv[4];
        #pragma unroll
        for (int i = 0; i < 4; ++i) cv[i] = Cs[(ty << 2) + i][n];
        #pragma unroll
        for (int j = 0; j < 4; ++j) { bv[j] = U1[(tx << 2) + j][n]; hv[j] = U2[(tx << 2) + j][n]; }
        #pragma unroll
        for (int i = 0; i < 4; ++i)
            #pragma unroll
            for (int j = 0; j < 4; ++j) {
                G[i][j]  += cv[i] * bv[j];
                CH[i][j] += cv[i] * hv[j];
            }
    }
    __syncthreads();
    #pragma unroll
    for (int i = 0; i < 4; ++i)
        #pragma unroll
        for (int j = 0; j < 4; ++j) {
            int s = (ty << 2) + i, r = (tx << 2) + j;
            float m = 0.f;
            if (r <= s) m = G[i][j] * __expf(La_sh[s] - La_sh[r]) * dt_sh[r];
            U1[s][r] = m;
        }
    for (int it = 0; it < 16; ++it) {
        int r = ls4 + 4 * it;
        U2[r][ln] = bf2f(conv_out[(size_t)(tokbase + r) * 640 + h * 64 + ln]);
    }
    __syncthreads();
    float Y[4][4];
    #pragma unroll
    for (int i = 0; i < 4; ++i)
        #pragma unroll
        for (int j = 0; j < 4; ++j)
            Y[i][j] = ce_sh[(ty << 2) + i] * CH[i][j];
    for (int r = 0; r < 64; ++r) {
        float mv[4], xv[4];
        #pragma unroll
        for (int i = 0; i < 4; ++i) mv[i] = U1[(ty << 2) + i][r];
        #pragma unroll
        for (int j = 0; j < 4; ++j) xv[j] = U2[r][(tx << 2) + j];
        #pragma unroll
        for (int i = 0; i < 4; ++i)
            #pragma unroll
            for (int j = 0; j < 4; ++j)
                Y[i][j] += mv[i] * xv[j];
    }
    #pragma unroll
    for (int i = 0; i < 4; ++i) {
        int s = (ty << 2) + i;
        st4(ybuf + (size_t)(tokbase + s) * 512 + h * 64 + (tx << 2), Y[i]);
    }
}

// ---------------- gate + RMSNorm, in-place on ybuf ----------------
__global__ __launch_bounds__(256) void gate_rms_kernel(
    bf16_t* __restrict__ y, const bf16_t* __restrict__ conv_out,
    const bf16_t* __restrict__ zx, const float* __restrict__ Dp,
    const float* __restrict__ rw)
{
    int row = blockIdx.x * 4 + (threadIdx.x >> 6);
    int lane = threadIdx.x & 63;
    uint4* yrow = (uint4*)(y + (size_t)row * 512);
    uint4 uy = yrow[lane];
    uint4 ux = *(const uint4*)(conv_out + (size_t)row * 640 + lane * 8);
    uint4 uz = *(const uint4*)(zx + (size_t)row * 1160 + lane * 8);
    float fy[8], fx[8], fz[8];
    unpack8(uy, fy); unpack8(ux, fx); unpack8(uz, fz);
    float d = Dp[lane >> 3];
    float v[8];
    float sq = 0.f;
    #pragma unroll
    for (int i = 0; i < 8; ++i) {
        v[i] = (fy[i] + d * fx[i]) * siluf(fz[i]);
        sq += v[i] * v[i];
    }
    #pragma unroll
    for (int off = 32; off; off >>= 1) sq += __shfl_xor(sq, off);
    float r = rsqrtf(sq * (1.f/512.f) + 1e-5f);
    float4 w0 = *(const float4*)(rw + lane * 8);
    float4 w1 = *(const float4*)(rw + lane * 8 + 4);
    float o[8];
    o[0] = v[0]*r*w0.x; o[1] = v[1]*r*w0.y; o[2] = v[2]*r*w0.z; o[3] = v[3]*r*w0.w;
    o[4] = v[4]*r*w1.x; o[5] = v[5]*r*w1.y; o[6] = v[6]*r*w1.z; o[7] = v[7]*r*w1.w;
    yrow[lane] = pack8(o);
}

// ---------------- final: out = LN(sp + m_out) ----------------
__global__ __launch_bounds__(256) void final_ln_kernel(
    const float* __restrict__ sp, const float* __restrict__ mo,
    const float* __restrict__ w, const float* __restrict__ b,
    float* __restrict__ out)
{
    int row = blockIdx.x * 4 + (threadIdx.x >> 6);
    int lane = threadIdx.x & 63;
    float4 a = ((const float4*)(sp + (size_t)row * 256))[lane];
    float4 c = ((const float4*)(mo + (size_t)row * 256))[lane];
    float4 v = {a.x + c.x, a.y + c.y, a.z + c.z, a.w + c.w};
    float s = v.x + v.y + v.z + v.w;
    float sq = v.x*v.x + v.y*v.y + v.z*v.z + v.w*v.w;
    #pragma unroll
    for (int off = 32; off; off >>= 1) { s += __shfl_xor(s, off); sq += __shfl_xor(sq, off); }
    float mu = s * (1.f/256.f);
    float var = sq * (1.f/256.f) - mu*mu;
    float inv = rsqrtf(var + 1e-5f);
    float4 wv = ((const float4*)w)[lane];
    float4 bv = ((const float4*)b)[lane];
    float4 o;
    o.x = (v.x-mu)*inv*wv.x + bv.x;
    o.y = (v.y-mu)*inv*wv.y + bv.y;
    o.z = (v.z-mu)*inv*wv.z + bv.z;
    o.w = (v.w-mu)*inv*wv.w + bv.w;
    ((float4*)(out + (size_t)row * 256))[lane] = o;
}

extern "C" void kernel_launch(void* const* d_in, const int* in_sizes, int n_in,
                              void* d_out, int out_size, void* d_ws, size_t ws_size,
                              hipStream_t stream) {
    (void)in_sizes; (void)n_in; (void)out_size; (void)ws_size;
    const float* x0      = (const float*)d_in[0];
    const float* x1      = (const float*)d_in[1];
    const float* nsw     = (const float*)d_in[2];
    const float* nsb     = (const float*)d_in[3];
    const float* W_in    = (const float*)d_in[4];
    const float* conv_w  = (const float*)d_in[5];
    const float* conv_b  = (const float*)d_in[6];
    const float* dt_bias = (const float*)d_in[7];
    const float* A_log   = (const float*)d_in[8];
    const float* D_param = (const float*)d_in[9];
    const float* rms_w   = (const float*)d_in[10];
    const float* W_out   = (const float*)d_in[11];
    const float* mlp_w1  = (const float*)d_in[12];
    const float* mlp_b1  = (const float*)d_in[13];
    const float* mlp_w2  = (const float*)d_in[14];
    const float* mlp_b2  = (const float*)d_in[15];
    const float* ntw     = (const float*)d_in[16];
    const float* ntb     = (const float*)d_in[17];
    float* out = (float*)d_out;

    // ---- workspace layout (bytes), total ~188.4 MB ----
    char* base = (char*)d_ws;
    // RA 76,021,760: zx bf16 (32768x1160) [steps 2-7]; then sp f32 (32768x256) [8-11]
    bf16_t* zx = (bf16_t*)base;
    float*  sp = (float*)base;
    char* pB = base + 76021760;
    // RB 41,943,040: convo bf16 (32768x640) [3-7]; then hbuf bf16 (32768x256) [9-10]
    bf16_t* convo = (bf16_t*)pB;
    bf16_t* hbuf  = (bf16_t*)pB;
    char* pC = pB + 41943040;
    // RC 33,554,432: x_norm bf16 (32768x256) [1-2]; then SH bf16 (64x64x4096) [4-6]
    bf16_t* x_norm = (bf16_t*)pC;
    bf16_t* SH     = (bf16_t*)pC;
    char* pD = pC + 33554432;
    // RD 33,554,432: ybuf bf16 (32768x512) [6-8]; then mout f32 (32768x256) [10-11]
    bf16_t* ybuf = (bf16_t*)pD;
    float*  mout = (float*)pD;
    char* pE = pD + 33554432;
    float* dts  = (float*)pE;            // 1,048,576 B
    float* lda  = dts + 262144;          // 1,048,576 B
    float* dtot = lda + 262144;          // 16,384 B
    bf16_t* Wb_in = (bf16_t*)(dtot + 4096);   // 1160x256 = 593,920 B
    bf16_t* Wb_o  = Wb_in + 296960;           // 256x512  = 262,144 B
    bf16_t* Wb_1  = Wb_o + 131072;            // 256x512  = 262,144 B
    bf16_t* Wb_2  = Wb_1 + 131072;            // 256x256  = 131,072 B

    // weight conversion (tiny)
    wconv_kernel<<<(74240 + 255) / 256, 256, 0, stream>>>(W_in,   Wb_in, 74240);
    wconv_kernel<<<(32768 + 255) / 256, 256, 0, stream>>>(W_out,  Wb_o,  32768);
    wconv_kernel<<<(32768 + 255) / 256, 256, 0, stream>>>(mlp_w1, Wb_1,  32768);
    wconv_kernel<<<(16384 + 255) / 256, 256, 0, stream>>>(mlp_w2, Wb_2,  16384);

    ln_cat_kernel<<<8192, 256, 0, stream>>>(x0, x1, nsw, nsb, x_norm);

    // in_proj: (32768 x 256) @ (1160 x 256)^T -> zx bf16
    dim3 g_in(256, 10);
    gemm_mfma<0, bf16_t, false, false, false><<<g_in, 256, 0, stream>>>(
        x_norm, Wb_in, nullptr, zx, nullptr, nullptr, NTOK, 1160, 256);

    conv_dt_kernel<<<NTOK, 256, 0, stream>>>(zx, conv_w, conv_b, dt_bias, A_log, convo, dts, lda);

    dim3 g_scan(64, 64);
    scan_passA<<<g_scan, 256, 0, stream>>>(convo, dts, lda, SH, dtot);
    dim3 g_pb(64, 16);
    scan_passB<<<g_pb, 256, 0, stream>>>(SH, dtot);
    scan_passC<<<g_scan, 256, 0, stream>>>(convo, dts, lda, SH, ybuf);

    gate_rms_kernel<<<8192, 256, 0, stream>>>(ybuf, convo, zx, D_param, rms_w);

    // out_proj + residual: (32768 x 512) @ (256 x 512)^T + x_cat -> sp f32
    dim3 g_out(256, 2);
    gemm_mfma<0, float, false, false, true><<<g_out, 256, 0, stream>>>(
        ybuf, Wb_o, nullptr, sp, x0, x1, NTOK, 256, 512);

    // mlp1: concat(sp[m], sp[m^HALF]) (32768 x 512) @ (256 x 512)^T + b1, SiLU -> hbuf bf16
    gemm_mfma<2, bf16_t, true, true, false><<<g_out, 256, 0, stream>>>(
        sp, Wb_1, mlp_b1, hbuf, nullptr, nullptr, NTOK, 256, 512);

    // mlp2: (32768 x 256) @ (256 x 256)^T + b2 -> mout f32
    gemm_mfma<0, float, true, false, false><<<g_out, 256, 0, stream>>>(
        hbuf, Wb_2, mlp_b2, mout, nullptr, nullptr, NTOK, 256, 256);

    final_ln_kernel<<<8192, 256, 0, stream>>>(sp, mout, ntw, ntb, out);
}

// Round 4
// 420.136 us; speedup vs baseline: 2.4997x; 1.3774x over previous
//
#include <hip/hip_runtime.h>
#include <math.h>

typedef unsigned short bf16_t;
typedef __attribute__((ext_vector_type(8))) short bf16x8;
typedef __attribute__((ext_vector_type(4))) float f32x4;

#define LSEQ 4096
#define NTOK 32768
#define HALF_TOK 16384
#define TPAD 72   // bf16 row stride for 64-col LDS tiles (144 B rows, 16B-aligned)

__device__ __forceinline__ float bf2f(bf16_t u) {
    unsigned int x = ((unsigned int)u) << 16;
    return __uint_as_float(x);
}
__device__ __forceinline__ bf16_t f2bf(float f) {
    unsigned int x = __float_as_uint(f);
    unsigned int r = (x + 0x7FFFu + ((x >> 16) & 1u)) >> 16;
    return (bf16_t)r;
}
__device__ __forceinline__ float siluf(float x) { return x / (1.f + __expf(-x)); }

__device__ __forceinline__ void unpack8(uint4 u, float* f) {
    f[0] = bf2f((bf16_t)(u.x & 0xffff)); f[1] = bf2f((bf16_t)(u.x >> 16));
    f[2] = bf2f((bf16_t)(u.y & 0xffff)); f[3] = bf2f((bf16_t)(u.y >> 16));
    f[4] = bf2f((bf16_t)(u.z & 0xffff)); f[5] = bf2f((bf16_t)(u.z >> 16));
    f[6] = bf2f((bf16_t)(u.w & 0xffff)); f[7] = bf2f((bf16_t)(u.w >> 16));
}
__device__ __forceinline__ uint4 pack8(const float* f) {
    uint4 u;
    u.x = (unsigned)f2bf(f[0]) | ((unsigned)f2bf(f[1]) << 16);
    u.y = (unsigned)f2bf(f[2]) | ((unsigned)f2bf(f[3]) << 16);
    u.z = (unsigned)f2bf(f[4]) | ((unsigned)f2bf(f[5]) << 16);
    u.w = (unsigned)f2bf(f[6]) | ((unsigned)f2bf(f[7]) << 16);
    return u;
}
__device__ __forceinline__ void st4(bf16_t* p, const float* o) {
    ushort4 u; u.x = f2bf(o[0]); u.y = f2bf(o[1]); u.z = f2bf(o[2]); u.w = f2bf(o[3]);
    *(ushort4*)p = u;
}

// natural stage: T[r][c] = g[r*rs + c]  (64x64 bf16, vectorized)
__device__ __forceinline__ void stage_N(bf16_t (*T)[TPAD], const bf16_t* g, int rs, int tid) {
    #pragma unroll
    for (int it = 0; it < 2; ++it) {
        int slot = it * 256 + tid;
        int r = slot >> 3, co = slot & 7;
        *(uint4*)&T[r][co * 8] = *(const uint4*)(g + (size_t)r * rs + co * 8);
    }
}

// transposed stage: T[c][r] = g[r*rs + c]  (64x64 bf16, packed-pair b32 writes)
__device__ __forceinline__ void stage_T(bf16_t (*T)[TPAD], const bf16_t* g, int rs, int tid) {
    int rp = tid >> 3;               // 0..31 row-pair
    int co = tid & 7;                // col octet
    int r0 = rp * 2;
    const bf16_t* p0 = g + (size_t)r0 * rs + co * 8;
    uint4 a = *(const uint4*)p0;
    uint4 b = *(const uint4*)(p0 + rs);
    unsigned aa[4] = {a.x, a.y, a.z, a.w};
    unsigned bb[4] = {b.x, b.y, b.z, b.w};
    #pragma unroll
    for (int q = 0; q < 4; ++q) {
        int c0 = co * 8 + q * 2;
        *(unsigned*)&T[c0][r0]     = (aa[q] & 0xffffu) | (bb[q] << 16 & 0xffff0000u);
        *(unsigned*)&T[c0 + 1][r0] = (aa[q] >> 16)     | (bb[q] & 0xffff0000u);
    }
}

// ---------------- weight f32 -> bf16 ----------------
__global__ __launch_bounds__(256) void wconv_kernel(
    const float* __restrict__ s, bf16_t* __restrict__ d, int n4)
{
    int i = blockIdx.x * 256 + threadIdx.x;
    if (i < n4) {
        float4 v = ((const float4*)s)[i];
        ushort4 u; u.x = f2bf(v.x); u.y = f2bf(v.y); u.z = f2bf(v.z); u.w = f2bf(v.w);
        ((ushort4*)d)[i] = u;
    }
}

// ---------------- LayerNorm over concat(x0,x1) -> bf16 ----------------
__global__ __launch_bounds__(256) void ln_cat_kernel(
    const float* __restrict__ x0, const float* __restrict__ x1,
    const float* __restrict__ w, const float* __restrict__ b,
    bf16_t* __restrict__ out)
{
    int row = blockIdx.x * 4 + (threadIdx.x >> 6);
    int lane = threadIdx.x & 63;
    const float* src = (row < HALF_TOK) ? x0 + (size_t)row * 256
                                        : x1 + (size_t)(row - HALF_TOK) * 256;
    float4 v = ((const float4*)src)[lane];
    float s = v.x + v.y + v.z + v.w;
    float sq = v.x*v.x + v.y*v.y + v.z*v.z + v.w*v.w;
    #pragma unroll
    for (int off = 32; off; off >>= 1) { s += __shfl_xor(s, off); sq += __shfl_xor(sq, off); }
    float mu = s * (1.f/256.f);
    float var = sq * (1.f/256.f) - mu*mu;
    float inv = rsqrtf(var + 1e-5f);
    float4 wv = ((const float4*)w)[lane];
    float4 bv = ((const float4*)b)[lane];
    float o[4];
    o[0] = (v.x-mu)*inv*wv.x + bv.x;
    o[1] = (v.y-mu)*inv*wv.y + bv.y;
    o[2] = (v.z-mu)*inv*wv.z + bv.z;
    o[3] = (v.w-mu)*inv*wv.w + bv.w;
    st4(out + (size_t)row * 256 + lane * 4, o);
}

// ---------------- MFMA GEMM: C = A(MxK) @ W(NxK)^T ----------------
template<int AMODE, typename TC, bool BIAS, bool SILU, bool RES>
__global__ __launch_bounds__(256) void gemm_mfma(
    const void* __restrict__ Avoid, const bf16_t* __restrict__ W,
    const float* __restrict__ bias, TC* __restrict__ C,
    const float* __restrict__ r0, const float* __restrict__ r1,
    int M, int N, int K)
{
    __shared__ bf16_t As[128][40];
    __shared__ bf16_t Ws[128][40];
    int tid = threadIdx.x;
    int m0 = blockIdx.x << 7, n0 = blockIdx.y << 7;
    int wave = tid >> 6, lane = tid & 63;
    int wr = wave >> 1, wc = wave & 1;
    int fr = lane & 15, fk = lane >> 4;

    f32x4 acc[4][4] = {};

    for (int k0 = 0; k0 < K; k0 += 32) {
        __syncthreads();
        #pragma unroll
        for (int ss = 0; ss < 2; ++ss) {
            int s = tid + ss * 256;
            int row = s >> 2, cs = s & 3;
            int kk = k0 + cs * 8;
            if (AMODE == 0) {
                const bf16_t* Ap = (const bf16_t*)Avoid;
                uint4 v = *(const uint4*)(Ap + (size_t)(m0 + row) * K + kk);
                *(uint4*)&As[row][cs * 8] = v;
            } else {
                const float* Ap = (const float*)Avoid;
                int m = m0 + row;
                const float* p = (AMODE == 1) ? (Ap + (size_t)m * K + kk)
                    : ((kk < 256) ? (Ap + (size_t)m * 256 + kk)
                                  : (Ap + (size_t)(m ^ HALF_TOK) * 256 + (kk - 256)));
                float4 f0 = *(const float4*)p, f1 = *(const float4*)(p + 4);
                float f[8] = {f0.x, f0.y, f0.z, f0.w, f1.x, f1.y, f1.z, f1.w};
                *(uint4*)&As[row][cs * 8] = pack8(f);
            }
            uint4 wv = make_uint4(0u, 0u, 0u, 0u);
            if (n0 + row < N) wv = *(const uint4*)(W + (size_t)(n0 + row) * K + kk);
            *(uint4*)&Ws[row][cs * 8] = wv;
        }
        __syncthreads();

        bf16x8 af[4], bf[4];
        #pragma unroll
        for (int i = 0; i < 4; ++i)
            af[i] = *(const bf16x8*)&As[wr * 64 + i * 16 + fr][fk * 8];
        #pragma unroll
        for (int j = 0; j < 4; ++j)
            bf[j] = *(const bf16x8*)&Ws[wc * 64 + j * 16 + fr][fk * 8];
        #pragma unroll
        for (int i = 0; i < 4; ++i)
            #pragma unroll
            for (int j = 0; j < 4; ++j)
                acc[i][j] = __builtin_amdgcn_mfma_f32_16x16x32_bf16(af[i], bf[j], acc[i][j], 0, 0, 0);
    }

    int fq = lane >> 4;
    #pragma unroll
    for (int j = 0; j < 4; ++j) {
        int n = n0 + wc * 64 + j * 16 + fr;
        if (n >= N) continue;
        float bval = BIAS ? bias[n] : 0.f;
        #pragma unroll
        for (int i = 0; i < 4; ++i) {
            #pragma unroll
            for (int q = 0; q < 4; ++q) {
                int m = m0 + wr * 64 + i * 16 + fq * 4 + q;
                float v = acc[i][j][q];
                if (BIAS) v += bval;
                if (SILU) v = siluf(v);
                if (RES) v += (m < HALF_TOK) ? r0[(size_t)m * 256 + n]
                                             : r1[(size_t)(m - HALF_TOK) * 256 + n];
                if (sizeof(TC) == 4) ((float*)C)[(size_t)m * N + n] = v;
                else ((bf16_t*)C)[(size_t)m * N + n] = f2bf(v);
            }
        }
    }
}

// ---------------- causal conv (width 4) + SiLU; dt=softplus, log(dA) ----------------
// 4 tokens per block, 80 threads per token (8 channels each, uint4 loads)
__global__ __launch_bounds__(320) void conv_dt_kernel(
    const bf16_t* __restrict__ zx, const float* __restrict__ cw,
    const float* __restrict__ cb, const float* __restrict__ dtb,
    const float* __restrict__ alog,
    bf16_t* __restrict__ conv_out, float* __restrict__ dts, float* __restrict__ lda)
{
    int tl = threadIdx.x / 80;
    int slot = threadIdx.x - tl * 80;
    int tok = blockIdx.x * 4 + tl;
    int b = tok >> 12, t = tok & 4095;
    int ch = slot * 8;

    float f[4][8];
    #pragma unroll
    for (int k = 0; k < 4; ++k) {
        int tp = t - 3 + k;
        if (tp >= 0) {
            uint4 u = *(const uint4*)(zx + (size_t)(b * LSEQ + tp) * 1160 + 512 + ch);
            unpack8(u, f[k]);
        } else {
            #pragma unroll
            for (int j = 0; j < 8; ++j) f[k][j] = 0.f;
        }
    }
    float o[8];
    #pragma unroll
    for (int j = 0; j < 8; ++j) {
        float4 w4 = *(const float4*)(cw + (ch + j) * 4);
        float acc = cb[ch + j] + w4.x * f[0][j] + w4.y * f[1][j] + w4.z * f[2][j] + w4.w * f[3][j];
        o[j] = siluf(acc);
    }
    *(uint4*)(conv_out + (size_t)tok * 640 + ch) = pack8(o);

    if (slot < 8) {
        int h = slot;
        float raw = bf2f(zx[(size_t)tok * 1160 + 1152 + h]) + dtb[h];
        float dt = (raw > 20.f) ? raw : log1pf(__expf(raw));
        dts[tok * 8 + h] = dt;
        lda[tok * 8 + h] = -dt * __expf(alog[h]);
    }
}

// ---------------- scan pass A (MFMA): S[p][n] = sum_s X[s][p]*wls[s] * B[s][n] ----------------
__global__ __launch_bounds__(256) void scan_passA(
    const bf16_t* __restrict__ conv_out, const float* __restrict__ dts,
    const float* __restrict__ lda, bf16_t* __restrict__ SH, float* __restrict__ Dtot)
{
    int bh = blockIdx.x, c = blockIdx.y;
    int b = bh >> 3, h = bh & 7;
    __shared__ bf16_t Xt[64][TPAD];   // Xt[p][s]
    __shared__ bf16_t Bw[64][TPAD];   // Bw[n][s] (scaled by wls[s])
    __shared__ float wls[64];
    int tid = threadIdx.x;
    int tokbase = b * LSEQ + c * 64;

    if (tid < 64) {
        float la = lda[(tokbase + tid) * 8 + h];
        #pragma unroll
        for (int off = 1; off < 64; off <<= 1) {
            float up = __shfl_up(la, off);
            if (tid >= off) la += up;
        }
        float tot = __shfl(la, 63);
        wls[tid] = __expf(tot - la) * dts[(tokbase + tid) * 8 + h];
        if (tid == 63) Dtot[bh * 64 + c] = __expf(tot);
    }
    stage_T(Xt, conv_out + (size_t)tokbase * 640 + h * 64, 640, tid);
    __syncthreads();

    // Bw[n][s] = B[s][n] * wls[s]   (transposed + scaled)
    {
        int rp = tid >> 3, co = tid & 7;
        int r0 = rp * 2;
        const bf16_t* p0 = conv_out + (size_t)(tokbase + r0) * 640 + 512 + co * 8;
        uint4 a = *(const uint4*)p0;
        uint4 bq = *(const uint4*)(p0 + 640);
        float fa[8], fb[8];
        unpack8(a, fa); unpack8(bq, fb);
        float w0 = wls[r0], w1 = wls[r0 + 1];
        #pragma unroll
        for (int q = 0; q < 8; ++q) {
            int c0 = co * 8 + q;
            *(unsigned*)&Bw[c0][r0] =
                (unsigned)f2bf(fa[q] * w0) | ((unsigned)f2bf(fb[q] * w1) << 16);
        }
    }
    __syncthreads();

    int wv = tid >> 6, lane = tid & 63;
    int fr = lane & 15, fk = lane >> 4;
    f32x4 acc[4] = {};
    bf16x8 af0 = *(const bf16x8*)&Xt[wv * 16 + fr][fk * 8];
    bf16x8 af1 = *(const bf16x8*)&Xt[wv * 16 + fr][32 + fk * 8];
    #pragma unroll
    for (int j = 0; j < 4; ++j) {
        bf16x8 b0 = *(const bf16x8*)&Bw[j * 16 + fr][fk * 8];
        bf16x8 b1 = *(const bf16x8*)&Bw[j * 16 + fr][32 + fk * 8];
        acc[j] = __builtin_amdgcn_mfma_f32_16x16x32_bf16(af0, b0, acc[j], 0, 0, 0);
        acc[j] = __builtin_amdgcn_mfma_f32_16x16x32_bf16(af1, b1, acc[j], 0, 0, 0);
    }
    __syncthreads();
    // bounce: Xt[p][n] = acc, then coalesced store
    #pragma unroll
    for (int j = 0; j < 4; ++j)
        #pragma unroll
        for (int q = 0; q < 4; ++q) {
            int p = wv * 16 + fk * 4 + q;
            Xt[p][j * 16 + fr] = f2bf(acc[j][q]);
        }
    __syncthreads();
    size_t base = (size_t)(bh * 64 + c) * 4096;
    #pragma unroll
    for (int it = 0; it < 2; ++it) {
        int slot = it * 256 + tid;
        int p = slot >> 3, co = slot & 7;
        *(uint4*)(SH + base + p * 64 + co * 8) = *(const uint4*)&Xt[p][co * 8];
    }
}

// ---------------- scan pass B: inter-chunk recurrence ----------------
__global__ __launch_bounds__(256) void scan_passB(bf16_t* __restrict__ SH, const float* __restrict__ Dtot)
{
    int bh = blockIdx.x;
    int elem = blockIdx.y * 256 + threadIdx.x;
    size_t base = (size_t)bh * 64 * 4096 + elem;
    float H = 0.f;
    for (int c = 0; c < 64; ++c) {
        float d = Dtot[bh * 64 + c];
        size_t a = base + (size_t)c * 4096;
        float s = bf2f(SH[a]);
        SH[a] = f2bf(H);
        H = d * H + s;
    }
}

// ---------------- scan pass C (MFMA) ----------------
__global__ __launch_bounds__(256) void scan_passC(
    const bf16_t* __restrict__ conv_out, const float* __restrict__ dts,
    const float* __restrict__ lda, const bf16_t* __restrict__ SH,
    bf16_t* __restrict__ ybuf)
{
    int bh = blockIdx.x, c = blockIdx.y;
    int b = bh >> 3, h = bh & 7;
    __shared__ bf16_t Cs[64][TPAD];   // C[s][n]; later M1[s][r]
    __shared__ bf16_t Bs[64][TPAD];   // B[r][n]; later Y[s][p]
    __shared__ bf16_t Hs[64][TPAD];   // H[p][n]
    __shared__ bf16_t Xt[64][TPAD];   // X^T[p][r]
    __shared__ float La_sh[64], dt_sh[64], ce_sh[64];
    int tid = threadIdx.x;
    int tokbase = b * LSEQ + c * 64;
    size_t shbase = (size_t)(bh * 64 + c) * 4096;

    if (tid < 64) {
        float la = lda[(tokbase + tid) * 8 + h];
        #pragma unroll
        for (int off = 1; off < 64; off <<= 1) {
            float up = __shfl_up(la, off);
            if (tid >= off) la += up;
        }
        La_sh[tid] = la;
        ce_sh[tid] = __expf(la);
        dt_sh[tid] = dts[(tokbase + tid) * 8 + h];
    }
    stage_N(Cs, conv_out + (size_t)tokbase * 640 + 576, 640, tid);
    stage_N(Bs, conv_out + (size_t)tokbase * 640 + 512, 640, tid);
    stage_N(Hs, SH + shbase, 64, tid);
    stage_T(Xt, conv_out + (size_t)tokbase * 640 + h * 64, 640, tid);
    __syncthreads();

    int wv = tid >> 6, lane = tid & 63;
    int fr = lane & 15, fk = lane >> 4;
    int ws = wv * 16;

    bf16x8 afC0 = *(const bf16x8*)&Cs[ws + fr][fk * 8];
    bf16x8 afC1 = *(const bf16x8*)&Cs[ws + fr][32 + fk * 8];
    f32x4 accG[4] = {}, accH[4] = {};
    #pragma unroll
    for (int j = 0; j < 4; ++j) {
        bf16x8 b0 = *(const bf16x8*)&Bs[j * 16 + fr][fk * 8];
        bf16x8 b1 = *(const bf16x8*)&Bs[j * 16 + fr][32 + fk * 8];
        accG[j] = __builtin_amdgcn_mfma_f32_16x16x32_bf16(afC0, b0, accG[j], 0, 0, 0);
        accG[j] = __builtin_amdgcn_mfma_f32_16x16x32_bf16(afC1, b1, accG[j], 0, 0, 0);
        bf16x8 h0 = *(const bf16x8*)&Hs[j * 16 + fr][fk * 8];
        bf16x8 h1 = *(const bf16x8*)&Hs[j * 16 + fr][32 + fk * 8];
        accH[j] = __builtin_amdgcn_mfma_f32_16x16x32_bf16(afC0, h0, accH[j], 0, 0, 0);
        accH[j] = __builtin_amdgcn_mfma_f32_16x16x32_bf16(afC1, h1, accH[j], 0, 0, 0);
    }

    // M1[s][r] = (r<=s) ? G * exp(La[s]-La[r]) * dt[r] : 0   -> own-stripe rows of Cs
    #pragma unroll
    for (int j = 0; j < 4; ++j)
        #pragma unroll
        for (int q = 0; q < 4; ++q) {
            int s = ws + fk * 4 + q;
            int r = j * 16 + fr;
            float m1 = 0.f;
            if (r <= s) m1 = accG[j][q] * __expf(La_sh[s] - La_sh[r]) * dt_sh[r];
            Cs[s][r] = f2bf(m1);
        }
    // Y init: ce[s] * CH
    #pragma unroll
    for (int j = 0; j < 4; ++j)
        #pragma unroll
        for (int q = 0; q < 4; ++q)
            accH[j][q] *= ce_sh[ws + fk * 4 + q];

    // Y += M1 @ X   (A = M1 rows own stripe, B = Xt rows p)
    bf16x8 afM0 = *(const bf16x8*)&Cs[ws + fr][fk * 8];
    bf16x8 afM1 = *(const bf16x8*)&Cs[ws + fr][32 + fk * 8];
    #pragma unroll
    for (int j = 0; j < 4; ++j) {
        bf16x8 x0 = *(const bf16x8*)&Xt[j * 16 + fr][fk * 8];
        bf16x8 x1 = *(const bf16x8*)&Xt[j * 16 + fr][32 + fk * 8];
        accH[j] = __builtin_amdgcn_mfma_f32_16x16x32_bf16(afM0, x0, accH[j], 0, 0, 0);
        accH[j] = __builtin_amdgcn_mfma_f32_16x16x32_bf16(afM1, x1, accH[j], 0, 0, 0);
    }

    __syncthreads();
    // bounce Y into Bs[s][p], coalesced store to ybuf
    #pragma unroll
    for (int j = 0; j < 4; ++j)
        #pragma unroll
        for (int q = 0; q < 4; ++q) {
            int s = ws + fk * 4 + q;
            Bs[s][j * 16 + fr] = f2bf(accH[j][q]);
        }
    __syncthreads();
    #pragma unroll
    for (int it = 0; it < 2; ++it) {
        int slot = it * 256 + tid;
        int r = slot >> 3, co = slot & 7;
        *(uint4*)(ybuf + (size_t)(tokbase + r) * 512 + h * 64 + co * 8) = *(const uint4*)&Bs[r][co * 8];
    }
}

// ---------------- gate + RMSNorm, in-place on ybuf ----------------
__global__ __launch_bounds__(256) void gate_rms_kernel(
    bf16_t* __restrict__ y, const bf16_t* __restrict__ conv_out,
    const bf16_t* __restrict__ zx, const float* __restrict__ Dp,
    const float* __restrict__ rw)
{
    int row = blockIdx.x * 4 + (threadIdx.x >> 6);
    int lane = threadIdx.x & 63;
    uint4* yrow = (uint4*)(y + (size_t)row * 512);
    uint4 uy = yrow[lane];
    uint4 ux = *(const uint4*)(conv_out + (size_t)row * 640 + lane * 8);
    uint4 uz = *(const uint4*)(zx + (size_t)row * 1160 + lane * 8);
    float fy[8], fx[8], fz[8];
    unpack8(uy, fy); unpack8(ux, fx); unpack8(uz, fz);
    float d = Dp[lane >> 3];
    float v[8];
    float sq = 0.f;
    #pragma unroll
    for (int i = 0; i < 8; ++i) {
        v[i] = (fy[i] + d * fx[i]) * siluf(fz[i]);
        sq += v[i] * v[i];
    }
    #pragma unroll
    for (int off = 32; off; off >>= 1) sq += __shfl_xor(sq, off);
    float r = rsqrtf(sq * (1.f/512.f) + 1e-5f);
    float4 w0 = *(const float4*)(rw + lane * 8);
    float4 w1 = *(const float4*)(rw + lane * 8 + 4);
    float o[8];
    o[0] = v[0]*r*w0.x; o[1] = v[1]*r*w0.y; o[2] = v[2]*r*w0.z; o[3] = v[3]*r*w0.w;
    o[4] = v[4]*r*w1.x; o[5] = v[5]*r*w1.y; o[6] = v[6]*r*w1.z; o[7] = v[7]*r*w1.w;
    yrow[lane] = pack8(o);
}

// ---------------- final: out = LN(sp + m_out) ----------------
__global__ __launch_bounds__(256) void final_ln_kernel(
    const float* __restrict__ sp, const float* __restrict__ mo,
    const float* __restrict__ w, const float* __restrict__ b,
    float* __restrict__ out)
{
    int row = blockIdx.x * 4 + (threadIdx.x >> 6);
    int lane = threadIdx.x & 63;
    float4 a = ((const float4*)(sp + (size_t)row * 256))[lane];
    float4 c = ((const float4*)(mo + (size_t)row * 256))[lane];
    float4 v = {a.x + c.x, a.y + c.y, a.z + c.z, a.w + c.w};
    float s = v.x + v.y + v.z + v.w;
    float sq = v.x*v.x + v.y*v.y + v.z*v.z + v.w*v.w;
    #pragma unroll
    for (int off = 32; off; off >>= 1) { s += __shfl_xor(s, off); sq += __shfl_xor(sq, off); }
    float mu = s * (1.f/256.f);
    float var = sq * (1.f/256.f) - mu*mu;
    float inv = rsqrtf(var + 1e-5f);
    float4 wv = ((const float4*)w)[lane];
    float4 bv = ((const float4*)b)[lane];
    float4 o;
    o.x = (v.x-mu)*inv*wv.x + bv.x;
    o.y = (v.y-mu)*inv*wv.y + bv.y;
    o.z = (v.z-mu)*inv*wv.z + bv.z;
    o.w = (v.w-mu)*inv*wv.w + bv.w;
    ((float4*)(out + (size_t)row * 256))[lane] = o;
}

extern "C" void kernel_launch(void* const* d_in, const int* in_sizes, int n_in,
                              void* d_out, int out_size, void* d_ws, size_t ws_size,
                              hipStream_t stream) {
    (void)in_sizes; (void)n_in; (void)out_size; (void)ws_size;
    const float* x0      = (const float*)d_in[0];
    const float* x1      = (const float*)d_in[1];
    const float* nsw     = (const float*)d_in[2];
    const float* nsb     = (const float*)d_in[3];
    const float* W_in    = (const float*)d_in[4];
    const float* conv_w  = (const float*)d_in[5];
    const float* conv_b  = (const float*)d_in[6];
    const float* dt_bias = (const float*)d_in[7];
    const float* A_log   = (const float*)d_in[8];
    const float* D_param = (const float*)d_in[9];
    const float* rms_w   = (const float*)d_in[10];
    const float* W_out   = (const float*)d_in[11];
    const float* mlp_w1  = (const float*)d_in[12];
    const float* mlp_b1  = (const float*)d_in[13];
    const float* mlp_w2  = (const float*)d_in[14];
    const float* mlp_b2  = (const float*)d_in[15];
    const float* ntw     = (const float*)d_in[16];
    const float* ntb     = (const float*)d_in[17];
    float* out = (float*)d_out;

    // ---- workspace layout (bytes), total ~188.4 MB ----
    char* base = (char*)d_ws;
    bf16_t* zx = (bf16_t*)base;           // 32768x1160 bf16
    float*  sp = (float*)base;            // later: 32768x256 f32
    char* pB = base + 76021760;
    bf16_t* convo = (bf16_t*)pB;          // 32768x640 bf16
    bf16_t* hbuf  = (bf16_t*)pB;          // later: 32768x256 bf16
    char* pC = pB + 41943040;
    bf16_t* x_norm = (bf16_t*)pC;         // 32768x256 bf16
    bf16_t* SH     = (bf16_t*)pC;         // later: 64x64x4096 bf16
    char* pD = pC + 33554432;
    bf16_t* ybuf = (bf16_t*)pD;           // 32768x512 bf16
    float*  mout = (float*)pD;            // later: 32768x256 f32
    char* pE = pD + 33554432;
    float* dts  = (float*)pE;
    float* lda  = dts + 262144;
    float* dtot = lda + 262144;
    bf16_t* Wb_in = (bf16_t*)(dtot + 4096);
    bf16_t* Wb_o  = Wb_in + 296960;
    bf16_t* Wb_1  = Wb_o + 131072;
    bf16_t* Wb_2  = Wb_1 + 131072;

    wconv_kernel<<<(74240 + 255) / 256, 256, 0, stream>>>(W_in,   Wb_in, 74240);
    wconv_kernel<<<(32768 + 255) / 256, 256, 0, stream>>>(W_out,  Wb_o,  32768);
    wconv_kernel<<<(32768 + 255) / 256, 256, 0, stream>>>(mlp_w1, Wb_1,  32768);
    wconv_kernel<<<(16384 + 255) / 256, 256, 0, stream>>>(mlp_w2, Wb_2,  16384);

    ln_cat_kernel<<<8192, 256, 0, stream>>>(x0, x1, nsw, nsb, x_norm);

    dim3 g_in(256, 10);
    gemm_mfma<0, bf16_t, false, false, false><<<g_in, 256, 0, stream>>>(
        x_norm, Wb_in, nullptr, zx, nullptr, nullptr, NTOK, 1160, 256);

    conv_dt_kernel<<<8192, 320, 0, stream>>>(zx, conv_w, conv_b, dt_bias, A_log, convo, dts, lda);

    dim3 g_scan(64, 64);
    scan_passA<<<g_scan, 256, 0, stream>>>(convo, dts, lda, SH, dtot);
    dim3 g_pb(64, 16);
    scan_passB<<<g_pb, 256, 0, stream>>>(SH, dtot);
    scan_passC<<<g_scan, 256, 0, stream>>>(convo, dts, lda, SH, ybuf);

    gate_rms_kernel<<<8192, 256, 0, stream>>>(ybuf, convo, zx, D_param, rms_w);

    dim3 g_out(256, 2);
    gemm_mfma<0, float, false, false, true><<<g_out, 256, 0, stream>>>(
        ybuf, Wb_o, nullptr, sp, x0, x1, NTOK, 256, 512);

    gemm_mfma<2, bf16_t, true, true, false><<<g_out, 256, 0, stream>>>(
        sp, Wb_1, mlp_b1, hbuf, nullptr, nullptr, NTOK, 256, 512);

    gemm_mfma<0, float, true, false, false><<<g_out, 256, 0, stream>>>(
        hbuf, Wb_2, mlp_b2, mout, nullptr, nullptr, NTOK, 256, 256);

    final_ln_kernel<<<8192, 256, 0, stream>>>(sp, mout, ntw, ntb, out);
}

// Round 5
// 397.676 us; speedup vs baseline: 2.6409x; 1.0565x over previous
//
#include <hip/hip_runtime.h>
#include <math.h>

typedef unsigned short bf16_t;
typedef __attribute__((ext_vector_type(8))) short bf16x8;
typedef __attribute__((ext_vector_type(4))) float f32x4;

#define LSEQ 4096
#define NTOK 32768
#define HALF_TOK 16384
#define TPAD 72   // bf16 row stride for 64-col LDS tiles (144 B rows, 16B-aligned)

__device__ __forceinline__ float bf2f(bf16_t u) {
    unsigned int x = ((unsigned int)u) << 16;
    return __uint_as_float(x);
}
__device__ __forceinline__ bf16_t f2bf(float f) {
    unsigned int x = __float_as_uint(f);
    unsigned int r = (x + 0x7FFFu + ((x >> 16) & 1u)) >> 16;
    return (bf16_t)r;
}
__device__ __forceinline__ float siluf(float x) { return x / (1.f + __expf(-x)); }

__device__ __forceinline__ void unpack8(uint4 u, float* f) {
    f[0] = bf2f((bf16_t)(u.x & 0xffff)); f[1] = bf2f((bf16_t)(u.x >> 16));
    f[2] = bf2f((bf16_t)(u.y & 0xffff)); f[3] = bf2f((bf16_t)(u.y >> 16));
    f[4] = bf2f((bf16_t)(u.z & 0xffff)); f[5] = bf2f((bf16_t)(u.z >> 16));
    f[6] = bf2f((bf16_t)(u.w & 0xffff)); f[7] = bf2f((bf16_t)(u.w >> 16));
}
__device__ __forceinline__ uint4 pack8(const float* f) {
    uint4 u;
    u.x = (unsigned)f2bf(f[0]) | ((unsigned)f2bf(f[1]) << 16);
    u.y = (unsigned)f2bf(f[2]) | ((unsigned)f2bf(f[3]) << 16);
    u.z = (unsigned)f2bf(f[4]) | ((unsigned)f2bf(f[5]) << 16);
    u.w = (unsigned)f2bf(f[6]) | ((unsigned)f2bf(f[7]) << 16);
    return u;
}
__device__ __forceinline__ void st4(bf16_t* p, const float* o) {
    ushort4 u; u.x = f2bf(o[0]); u.y = f2bf(o[1]); u.z = f2bf(o[2]); u.w = f2bf(o[3]);
    *(ushort4*)p = u;
}

// async global->LDS, 16B per lane, dest = wave-uniform base + lane*16
__device__ __forceinline__ void gload16(const bf16_t* g, bf16_t* l) {
    __builtin_amdgcn_global_load_lds(
        (const __attribute__((address_space(1))) unsigned int*)g,
        (__attribute__((address_space(3))) unsigned int*)l,
        16, 0, 0);
}

// natural stage: T[r][c] = g[r*rs + c]  (64x64 bf16, vectorized)
__device__ __forceinline__ void stage_N(bf16_t (*T)[TPAD], const bf16_t* g, int rs, int tid) {
    #pragma unroll
    for (int it = 0; it < 2; ++it) {
        int slot = it * 256 + tid;
        int r = slot >> 3, co = slot & 7;
        *(uint4*)&T[r][co * 8] = *(const uint4*)(g + (size_t)r * rs + co * 8);
    }
}

// transposed stage: T[c][r] = g[r*rs + c]  (64x64 bf16, packed-pair b32 writes)
__device__ __forceinline__ void stage_T(bf16_t (*T)[TPAD], const bf16_t* g, int rs, int tid) {
    int rp = tid >> 3;               // 0..31 row-pair
    int co = tid & 7;                // col octet
    int r0 = rp * 2;
    const bf16_t* p0 = g + (size_t)r0 * rs + co * 8;
    uint4 a = *(const uint4*)p0;
    uint4 b = *(const uint4*)(p0 + rs);
    unsigned aa[4] = {a.x, a.y, a.z, a.w};
    unsigned bb[4] = {b.x, b.y, b.z, b.w};
    #pragma unroll
    for (int q = 0; q < 4; ++q) {
        int c0 = co * 8 + q * 2;
        *(unsigned*)&T[c0][r0]     = (aa[q] & 0xffffu) | (bb[q] << 16 & 0xffff0000u);
        *(unsigned*)&T[c0 + 1][r0] = (aa[q] >> 16)     | (bb[q] & 0xffff0000u);
    }
}

// ---------------- weight f32 -> bf16 ----------------
__global__ __launch_bounds__(256) void wconv_kernel(
    const float* __restrict__ s, bf16_t* __restrict__ d, int n4)
{
    int i = blockIdx.x * 256 + threadIdx.x;
    if (i < n4) {
        float4 v = ((const float4*)s)[i];
        ushort4 u; u.x = f2bf(v.x); u.y = f2bf(v.y); u.z = f2bf(v.z); u.w = f2bf(v.w);
        ((ushort4*)d)[i] = u;
    }
}

// ---------------- LayerNorm over concat(x0,x1) -> bf16 ----------------
__global__ __launch_bounds__(256) void ln_cat_kernel(
    const float* __restrict__ x0, const float* __restrict__ x1,
    const float* __restrict__ w, const float* __restrict__ b,
    bf16_t* __restrict__ out)
{
    int row = blockIdx.x * 4 + (threadIdx.x >> 6);
    int lane = threadIdx.x & 63;
    const float* src = (row < HALF_TOK) ? x0 + (size_t)row * 256
                                        : x1 + (size_t)(row - HALF_TOK) * 256;
    float4 v = ((const float4*)src)[lane];
    float s = v.x + v.y + v.z + v.w;
    float sq = v.x*v.x + v.y*v.y + v.z*v.z + v.w*v.w;
    #pragma unroll
    for (int off = 32; off; off >>= 1) { s += __shfl_xor(s, off); sq += __shfl_xor(sq, off); }
    float mu = s * (1.f/256.f);
    float var = sq * (1.f/256.f) - mu*mu;
    float inv = rsqrtf(var + 1e-5f);
    float4 wv = ((const float4*)w)[lane];
    float4 bv = ((const float4*)b)[lane];
    float o[4];
    o[0] = (v.x-mu)*inv*wv.x + bv.x;
    o[1] = (v.y-mu)*inv*wv.y + bv.y;
    o[2] = (v.z-mu)*inv*wv.z + bv.z;
    o[3] = (v.w-mu)*inv*wv.w + bv.w;
    st4(out + (size_t)row * 256 + lane * 4, o);
}

// ---------------- MFMA GEMM (m97 structure): C = A(MxK) @ W(NxK)^T ----------------
// BM=BN=128, BK=64, 4 waves (2x2 of 64x64), global_load_lds staging with
// XOR-swizzled source (chunk ^= row&7), linear LDS [128][64].
// AMODE: 0 = A bf16 row-major (stride K); 1 = A bf16 concat: row m cols [0,256)
//        from A[m], cols [256,512) from A[m^HALF_TOK] (A stride 256).
template<int AMODE, typename TC, bool BIAS, bool SILU, bool RES, bool DUAL>
__global__ __launch_bounds__(256) void gemm_mfma(
    const bf16_t* __restrict__ A, const bf16_t* __restrict__ W,
    const float* __restrict__ bias, TC* __restrict__ C,
    const float* __restrict__ r0, const float* __restrict__ r1,
    bf16_t* __restrict__ C2,
    int M, int N, int K)
{
    __shared__ bf16_t As[128 * 64];
    __shared__ bf16_t Ws[128 * 64];
    const int tid = threadIdx.x;
    const int wave = tid >> 6, lane = tid & 63;
    const int m0 = blockIdx.x << 7, n0 = blockIdx.y << 7;
    const int wr = wave >> 1, wc = wave & 1;
    const int fr = lane & 15, fk = lane >> 4;

    const int srow = lane >> 3;             // 0..7 (row within 8-row group)
    const int schunk = (lane & 7) ^ srow;   // pre-swizzled 16B chunk in 128B row

    f32x4 acc[4][4] = {};

    for (int k0 = 0; k0 < K; k0 += 64) {
        __syncthreads();
        #pragma unroll
        for (int t = 0; t < 4; ++t) {
            int row = wave * 32 + t * 8 + srow;
            const bf16_t* ga;
            if (AMODE == 0) {
                ga = A + (size_t)(m0 + row) * K + k0 + schunk * 8;
            } else {
                int m = m0 + row;
                if (k0 < 256) ga = A + (size_t)m * 256 + k0 + schunk * 8;
                else          ga = A + (size_t)(m ^ HALF_TOK) * 256 + (k0 - 256) + schunk * 8;
            }
            gload16(ga, As + wave * 2048 + t * 512);
            const bf16_t* gw = W + (size_t)(n0 + row) * K + k0 + schunk * 8;
            gload16(gw, Ws + wave * 2048 + t * 512);
        }
        __syncthreads();   // compiler emits vmcnt(0) drain here

        #pragma unroll
        for (int half = 0; half < 2; ++half) {
            bf16x8 af[4], bfr[4];
            #pragma unroll
            for (int i = 0; i < 4; ++i) {
                int row = wr * 64 + i * 16 + fr;
                int c16 = (half * 4 + fk) ^ (row & 7);
                af[i] = *(const bf16x8*)&As[row * 64 + c16 * 8];
            }
            #pragma unroll
            for (int j = 0; j < 4; ++j) {
                int row = wc * 64 + j * 16 + fr;
                int c16 = (half * 4 + fk) ^ (row & 7);
                bfr[j] = *(const bf16x8*)&Ws[row * 64 + c16 * 8];
            }
            #pragma unroll
            for (int i = 0; i < 4; ++i)
                #pragma unroll
                for (int j = 0; j < 4; ++j)
                    acc[i][j] = __builtin_amdgcn_mfma_f32_16x16x32_bf16(af[i], bfr[j], acc[i][j], 0, 0, 0);
        }
    }

    // epilogue: m = m0+wr*64+i*16+fq*4+q, n = n0+wc*64+j*16+fr
    int fq = lane >> 4;
    #pragma unroll
    for (int j = 0; j < 4; ++j) {
        int n = n0 + wc * 64 + j * 16 + fr;
        if (n >= N) continue;
        float bval = BIAS ? bias[n] : 0.f;
        #pragma unroll
        for (int i = 0; i < 4; ++i) {
            #pragma unroll
            for (int q = 0; q < 4; ++q) {
                int m = m0 + wr * 64 + i * 16 + fq * 4 + q;
                float v = acc[i][j][q];
                if (BIAS) v += bval;
                if (SILU) v = siluf(v);
                if (RES) v += (m < HALF_TOK) ? r0[(size_t)m * 256 + n]
                                             : r1[(size_t)(m - HALF_TOK) * 256 + n];
                if (sizeof(TC) == 4) ((float*)C)[(size_t)m * N + n] = v;
                else ((bf16_t*)C)[(size_t)m * N + n] = f2bf(v);
                if (DUAL) C2[(size_t)m * N + n] = f2bf(v);
            }
        }
    }
}

// ---------------- causal conv (width 4) + SiLU; dt=softplus, log(dA) ----------------
__global__ __launch_bounds__(320) void conv_dt_kernel(
    const bf16_t* __restrict__ zx, const float* __restrict__ cw,
    const float* __restrict__ cb, const float* __restrict__ dtb,
    const float* __restrict__ alog,
    bf16_t* __restrict__ conv_out, float* __restrict__ dts, float* __restrict__ lda)
{
    int tl = threadIdx.x / 80;
    int slot = threadIdx.x - tl * 80;
    int tok = blockIdx.x * 4 + tl;
    int b = tok >> 12, t = tok & 4095;
    int ch = slot * 8;

    float f[4][8];
    #pragma unroll
    for (int k = 0; k < 4; ++k) {
        int tp = t - 3 + k;
        if (tp >= 0) {
            uint4 u = *(const uint4*)(zx + (size_t)(b * LSEQ + tp) * 1160 + 512 + ch);
            unpack8(u, f[k]);
        } else {
            #pragma unroll
            for (int j = 0; j < 8; ++j) f[k][j] = 0.f;
        }
    }
    float o[8];
    #pragma unroll
    for (int j = 0; j < 8; ++j) {
        float4 w4 = *(const float4*)(cw + (ch + j) * 4);
        float acc = cb[ch + j] + w4.x * f[0][j] + w4.y * f[1][j] + w4.z * f[2][j] + w4.w * f[3][j];
        o[j] = siluf(acc);
    }
    *(uint4*)(conv_out + (size_t)tok * 640 + ch) = pack8(o);

    if (slot < 8) {
        int h = slot;
        float raw = bf2f(zx[(size_t)tok * 1160 + 1152 + h]) + dtb[h];
        float dt = (raw > 20.f) ? raw : log1pf(__expf(raw));
        dts[tok * 8 + h] = dt;
        lda[tok * 8 + h] = -dt * __expf(alog[h]);
    }
}

// ---------------- scan pass A (MFMA): S[p][n] = sum_s X[s][p]*wls[s] * B[s][n] ----------------
__global__ __launch_bounds__(256) void scan_passA(
    const bf16_t* __restrict__ conv_out, const float* __restrict__ dts,
    const float* __restrict__ lda, bf16_t* __restrict__ SH, float* __restrict__ Dtot)
{
    int bh = blockIdx.x, c = blockIdx.y;
    int b = bh >> 3, h = bh & 7;
    __shared__ bf16_t Xt[64][TPAD];   // Xt[p][s]
    __shared__ bf16_t Bw[64][TPAD];   // Bw[n][s] (scaled by wls[s])
    __shared__ float wls[64];
    int tid = threadIdx.x;
    int tokbase = b * LSEQ + c * 64;

    if (tid < 64) {
        float la = lda[(tokbase + tid) * 8 + h];
        #pragma unroll
        for (int off = 1; off < 64; off <<= 1) {
            float up = __shfl_up(la, off);
            if (tid >= off) la += up;
        }
        float tot = __shfl(la, 63);
        wls[tid] = __expf(tot - la) * dts[(tokbase + tid) * 8 + h];
        if (tid == 63) Dtot[bh * 64 + c] = __expf(tot);
    }
    stage_T(Xt, conv_out + (size_t)tokbase * 640 + h * 64, 640, tid);
    __syncthreads();

    {
        int rp = tid >> 3, co = tid & 7;
        int r0 = rp * 2;
        const bf16_t* p0 = conv_out + (size_t)(tokbase + r0) * 640 + 512 + co * 8;
        uint4 a = *(const uint4*)p0;
        uint4 bq = *(const uint4*)(p0 + 640);
        float fa[8], fb[8];
        unpack8(a, fa); unpack8(bq, fb);
        float w0 = wls[r0], w1 = wls[r0 + 1];
        #pragma unroll
        for (int q = 0; q < 8; ++q) {
            int c0 = co * 8 + q;
            *(unsigned*)&Bw[c0][r0] =
                (unsigned)f2bf(fa[q] * w0) | ((unsigned)f2bf(fb[q] * w1) << 16);
        }
    }
    __syncthreads();

    int wv = tid >> 6, lane = tid & 63;
    int fr = lane & 15, fk = lane >> 4;
    f32x4 acc[4] = {};
    bf16x8 af0 = *(const bf16x8*)&Xt[wv * 16 + fr][fk * 8];
    bf16x8 af1 = *(const bf16x8*)&Xt[wv * 16 + fr][32 + fk * 8];
    #pragma unroll
    for (int j = 0; j < 4; ++j) {
        bf16x8 b0 = *(const bf16x8*)&Bw[j * 16 + fr][fk * 8];
        bf16x8 b1 = *(const bf16x8*)&Bw[j * 16 + fr][32 + fk * 8];
        acc[j] = __builtin_amdgcn_mfma_f32_16x16x32_bf16(af0, b0, acc[j], 0, 0, 0);
        acc[j] = __builtin_amdgcn_mfma_f32_16x16x32_bf16(af1, b1, acc[j], 0, 0, 0);
    }
    __syncthreads();
    #pragma unroll
    for (int j = 0; j < 4; ++j)
        #pragma unroll
        for (int q = 0; q < 4; ++q) {
            int p = wv * 16 + fk * 4 + q;
            Xt[p][j * 16 + fr] = f2bf(acc[j][q]);
        }
    __syncthreads();
    size_t base = (size_t)(bh * 64 + c) * 4096;
    #pragma unroll
    for (int it = 0; it < 2; ++it) {
        int slot = it * 256 + tid;
        int p = slot >> 3, co = slot & 7;
        *(uint4*)(SH + base + p * 64 + co * 8) = *(const uint4*)&Xt[p][co * 8];
    }
}

// ---------------- scan pass B: inter-chunk recurrence ----------------
__global__ __launch_bounds__(256) void scan_passB(bf16_t* __restrict__ SH, const float* __restrict__ Dtot)
{
    int bh = blockIdx.x;
    int elem = blockIdx.y * 256 + threadIdx.x;
    size_t base = (size_t)bh * 64 * 4096 + elem;
    float H = 0.f;
    for (int c = 0; c < 64; ++c) {
        float d = Dtot[bh * 64 + c];
        size_t a = base + (size_t)c * 4096;
        float s = bf2f(SH[a]);
        SH[a] = f2bf(H);
        H = d * H + s;
    }
}

// ---------------- scan pass C (MFMA) ----------------
__global__ __launch_bounds__(256) void scan_passC(
    const bf16_t* __restrict__ conv_out, const float* __restrict__ dts,
    const float* __restrict__ lda, const bf16_t* __restrict__ SH,
    bf16_t* __restrict__ ybuf)
{
    int bh = blockIdx.x, c = blockIdx.y;
    int b = bh >> 3, h = bh & 7;
    __shared__ bf16_t Cs[64][TPAD];   // C[s][n]; later M1[s][r]
    __shared__ bf16_t Bs[64][TPAD];   // B[r][n]; later Y[s][p]
    __shared__ bf16_t Hs[64][TPAD];   // H[p][n]
    __shared__ bf16_t Xt[64][TPAD];   // X^T[p][r]
    __shared__ float La_sh[64], dt_sh[64], ce_sh[64];
    int tid = threadIdx.x;
    int tokbase = b * LSEQ + c * 64;
    size_t shbase = (size_t)(bh * 64 + c) * 4096;

    if (tid < 64) {
        float la = lda[(tokbase + tid) * 8 + h];
        #pragma unroll
        for (int off = 1; off < 64; off <<= 1) {
            float up = __shfl_up(la, off);
            if (tid >= off) la += up;
        }
        La_sh[tid] = la;
        ce_sh[tid] = __expf(la);
        dt_sh[tid] = dts[(tokbase + tid) * 8 + h];
    }
    stage_N(Cs, conv_out + (size_t)tokbase * 640 + 576, 640, tid);
    stage_N(Bs, conv_out + (size_t)tokbase * 640 + 512, 640, tid);
    stage_N(Hs, SH + shbase, 64, tid);
    stage_T(Xt, conv_out + (size_t)tokbase * 640 + h * 64, 640, tid);
    __syncthreads();

    int wv = tid >> 6, lane = tid & 63;
    int fr = lane & 15, fk = lane >> 4;
    int ws = wv * 16;

    bf16x8 afC0 = *(const bf16x8*)&Cs[ws + fr][fk * 8];
    bf16x8 afC1 = *(const bf16x8*)&Cs[ws + fr][32 + fk * 8];
    f32x4 accG[4] = {}, accH[4] = {};
    #pragma unroll
    for (int j = 0; j < 4; ++j) {
        bf16x8 b0 = *(const bf16x8*)&Bs[j * 16 + fr][fk * 8];
        bf16x8 b1 = *(const bf16x8*)&Bs[j * 16 + fr][32 + fk * 8];
        accG[j] = __builtin_amdgcn_mfma_f32_16x16x32_bf16(afC0, b0, accG[j], 0, 0, 0);
        accG[j] = __builtin_amdgcn_mfma_f32_16x16x32_bf16(afC1, b1, accG[j], 0, 0, 0);
        bf16x8 h0 = *(const bf16x8*)&Hs[j * 16 + fr][fk * 8];
        bf16x8 h1 = *(const bf16x8*)&Hs[j * 16 + fr][32 + fk * 8];
        accH[j] = __builtin_amdgcn_mfma_f32_16x16x32_bf16(afC0, h0, accH[j], 0, 0, 0);
        accH[j] = __builtin_amdgcn_mfma_f32_16x16x32_bf16(afC1, h1, accH[j], 0, 0, 0);
    }

    #pragma unroll
    for (int j = 0; j < 4; ++j)
        #pragma unroll
        for (int q = 0; q < 4; ++q) {
            int s = ws + fk * 4 + q;
            int r = j * 16 + fr;
            float m1 = 0.f;
            if (r <= s) m1 = accG[j][q] * __expf(La_sh[s] - La_sh[r]) * dt_sh[r];
            Cs[s][r] = f2bf(m1);
        }
    #pragma unroll
    for (int j = 0; j < 4; ++j)
        #pragma unroll
        for (int q = 0; q < 4; ++q)
            accH[j][q] *= ce_sh[ws + fk * 4 + q];

    bf16x8 afM0 = *(const bf16x8*)&Cs[ws + fr][fk * 8];
    bf16x8 afM1 = *(const bf16x8*)&Cs[ws + fr][32 + fk * 8];
    #pragma unroll
    for (int j = 0; j < 4; ++j) {
        bf16x8 x0 = *(const bf16x8*)&Xt[j * 16 + fr][fk * 8];
        bf16x8 x1 = *(const bf16x8*)&Xt[j * 16 + fr][32 + fk * 8];
        accH[j] = __builtin_amdgcn_mfma_f32_16x16x32_bf16(afM0, x0, accH[j], 0, 0, 0);
        accH[j] = __builtin_amdgcn_mfma_f32_16x16x32_bf16(afM1, x1, accH[j], 0, 0, 0);
    }

    __syncthreads();
    #pragma unroll
    for (int j = 0; j < 4; ++j)
        #pragma unroll
        for (int q = 0; q < 4; ++q) {
            int s = ws + fk * 4 + q;
            Bs[s][j * 16 + fr] = f2bf(accH[j][q]);
        }
    __syncthreads();
    #pragma unroll
    for (int it = 0; it < 2; ++it) {
        int slot = it * 256 + tid;
        int r = slot >> 3, co = slot & 7;
        *(uint4*)(ybuf + (size_t)(tokbase + r) * 512 + h * 64 + co * 8) = *(const uint4*)&Bs[r][co * 8];
    }
}

// ---------------- gate + RMSNorm, in-place on ybuf ----------------
__global__ __launch_bounds__(256) void gate_rms_kernel(
    bf16_t* __restrict__ y, const bf16_t* __restrict__ conv_out,
    const bf16_t* __restrict__ zx, const float* __restrict__ Dp,
    const float* __restrict__ rw)
{
    int row = blockIdx.x * 4 + (threadIdx.x >> 6);
    int lane = threadIdx.x & 63;
    uint4* yrow = (uint4*)(y + (size_t)row * 512);
    uint4 uy = yrow[lane];
    uint4 ux = *(const uint4*)(conv_out + (size_t)row * 640 + lane * 8);
    uint4 uz = *(const uint4*)(zx + (size_t)row * 1160 + lane * 8);
    float fy[8], fx[8], fz[8];
    unpack8(uy, fy); unpack8(ux, fx); unpack8(uz, fz);
    float d = Dp[lane >> 3];
    float v[8];
    float sq = 0.f;
    #pragma unroll
    for (int i = 0; i < 8; ++i) {
        v[i] = (fy[i] + d * fx[i]) * siluf(fz[i]);
        sq += v[i] * v[i];
    }
    #pragma unroll
    for (int off = 32; off; off >>= 1) sq += __shfl_xor(sq, off);
    float r = rsqrtf(sq * (1.f/512.f) + 1e-5f);
    float4 w0 = *(const float4*)(rw + lane * 8);
    float4 w1 = *(const float4*)(rw + lane * 8 + 4);
    float o[8];
    o[0] = v[0]*r*w0.x; o[1] = v[1]*r*w0.y; o[2] = v[2]*r*w0.z; o[3] = v[3]*r*w0.w;
    o[4] = v[4]*r*w1.x; o[5] = v[5]*r*w1.y; o[6] = v[6]*r*w1.z; o[7] = v[7]*r*w1.w;
    yrow[lane] = pack8(o);
}

// ---------------- final: out = LN(sp + m_out) ----------------
__global__ __launch_bounds__(256) void final_ln_kernel(
    const float* __restrict__ sp, const float* __restrict__ mo,
    const float* __restrict__ w, const float* __restrict__ b,
    float* __restrict__ out)
{
    int row = blockIdx.x * 4 + (threadIdx.x >> 6);
    int lane = threadIdx.x & 63;
    float4 a = ((const float4*)(sp + (size_t)row * 256))[lane];
    float4 c = ((const float4*)(mo + (size_t)row * 256))[lane];
    float4 v = {a.x + c.x, a.y + c.y, a.z + c.z, a.w + c.w};
    float s = v.x + v.y + v.z + v.w;
    float sq = v.x*v.x + v.y*v.y + v.z*v.z + v.w*v.w;
    #pragma unroll
    for (int off = 32; off; off >>= 1) { s += __shfl_xor(s, off); sq += __shfl_xor(sq, off); }
    float mu = s * (1.f/256.f);
    float var = sq * (1.f/256.f) - mu*mu;
    float inv = rsqrtf(var + 1e-5f);
    float4 wv = ((const float4*)w)[lane];
    float4 bv = ((const float4*)b)[lane];
    float4 o;
    o.x = (v.x-mu)*inv*wv.x + bv.x;
    o.y = (v.y-mu)*inv*wv.y + bv.y;
    o.z = (v.z-mu)*inv*wv.z + bv.z;
    o.w = (v.w-mu)*inv*wv.w + bv.w;
    ((float4*)(out + (size_t)row * 256))[lane] = o;
}

extern "C" void kernel_launch(void* const* d_in, const int* in_sizes, int n_in,
                              void* d_out, int out_size, void* d_ws, size_t ws_size,
                              hipStream_t stream) {
    (void)in_sizes; (void)n_in; (void)out_size; (void)ws_size;
    const float* x0      = (const float*)d_in[0];
    const float* x1      = (const float*)d_in[1];
    const float* nsw     = (const float*)d_in[2];
    const float* nsb     = (const float*)d_in[3];
    const float* W_in    = (const float*)d_in[4];
    const float* conv_w  = (const float*)d_in[5];
    const float* conv_b  = (const float*)d_in[6];
    const float* dt_bias = (const float*)d_in[7];
    const float* A_log   = (const float*)d_in[8];
    const float* D_param = (const float*)d_in[9];
    const float* rms_w   = (const float*)d_in[10];
    const float* W_out   = (const float*)d_in[11];
    const float* mlp_w1  = (const float*)d_in[12];
    const float* mlp_b1  = (const float*)d_in[13];
    const float* mlp_w2  = (const float*)d_in[14];
    const float* mlp_b2  = (const float*)d_in[15];
    const float* ntw     = (const float*)d_in[16];
    const float* ntb     = (const float*)d_in[17];
    float* out = (float*)d_out;

    // ---- workspace layout (bytes), total ~188.4 MB ----
    char* base = (char*)d_ws;
    bf16_t* zx = (bf16_t*)base;           // 32768x1160 bf16 [in_proj..gate]
    float*  sp = (float*)base;            // later: 32768x256 f32 [out_proj..final]
    char* pB = base + 76021760;
    bf16_t* convo = (bf16_t*)pB;          // 32768x640 bf16 [conv..gate]
    bf16_t* hbuf  = (bf16_t*)pB;          // later: 32768x256 bf16 [mlp1..mlp2]
    char* pC = pB + 41943040;
    bf16_t* x_norm = (bf16_t*)pC;         // 32768x256 bf16 [ln..in_proj]
    bf16_t* SH     = (bf16_t*)pC;         // 64x64x4096 bf16 [passA..passC]
    bf16_t* spb    = (bf16_t*)pC;         // later: 32768x256 bf16 [out_proj..mlp1]
    char* pD = pC + 33554432;
    bf16_t* ybuf = (bf16_t*)pD;           // 32768x512 bf16 [passC..out_proj]
    float*  mout = (float*)pD;            // later: 32768x256 f32 [mlp2..final]
    char* pE = pD + 33554432;
    float* dts  = (float*)pE;
    float* lda  = dts + 262144;
    float* dtot = lda + 262144;
    bf16_t* Wb_in = (bf16_t*)(dtot + 4096);
    bf16_t* Wb_o  = Wb_in + 296960;
    bf16_t* Wb_1  = Wb_o + 131072;
    bf16_t* Wb_2  = Wb_1 + 131072;

    wconv_kernel<<<(74240 + 255) / 256, 256, 0, stream>>>(W_in,   Wb_in, 74240);
    wconv_kernel<<<(32768 + 255) / 256, 256, 0, stream>>>(W_out,  Wb_o,  32768);
    wconv_kernel<<<(32768 + 255) / 256, 256, 0, stream>>>(mlp_w1, Wb_1,  32768);
    wconv_kernel<<<(16384 + 255) / 256, 256, 0, stream>>>(mlp_w2, Wb_2,  16384);

    ln_cat_kernel<<<8192, 256, 0, stream>>>(x0, x1, nsw, nsb, x_norm);

    // in_proj: (32768 x 256) @ (1160 x 256)^T -> zx bf16
    dim3 g_in(256, 10);
    gemm_mfma<0, bf16_t, false, false, false, false><<<g_in, 256, 0, stream>>>(
        x_norm, Wb_in, nullptr, zx, nullptr, nullptr, nullptr, NTOK, 1160, 256);

    conv_dt_kernel<<<8192, 320, 0, stream>>>(zx, conv_w, conv_b, dt_bias, A_log, convo, dts, lda);

    dim3 g_scan(64, 64);
    scan_passA<<<g_scan, 256, 0, stream>>>(convo, dts, lda, SH, dtot);
    dim3 g_pb(64, 16);
    scan_passB<<<g_pb, 256, 0, stream>>>(SH, dtot);
    scan_passC<<<g_scan, 256, 0, stream>>>(convo, dts, lda, SH, ybuf);

    gate_rms_kernel<<<8192, 256, 0, stream>>>(ybuf, convo, zx, D_param, rms_w);

    // out_proj + residual: (32768x512)@(256x512)^T + x_cat -> sp f32, spb bf16
    dim3 g_out(256, 2);
    gemm_mfma<0, float, false, false, true, true><<<g_out, 256, 0, stream>>>(
        ybuf, Wb_o, nullptr, sp, x0, x1, spb, NTOK, 256, 512);

    // mlp1: concat(spb[m], spb[m^HALF]) (32768x512)@(256x512)^T + b1, SiLU -> hbuf bf16
    gemm_mfma<1, bf16_t, true, true, false, false><<<g_out, 256, 0, stream>>>(
        spb, Wb_1, mlp_b1, hbuf, nullptr, nullptr, nullptr, NTOK, 256, 512);

    // mlp2: (32768x256)@(256x256)^T + b2 -> mout f32
    gemm_mfma<0, float, true, false, false, false><<<g_out, 256, 0, stream>>>(
        hbuf, Wb_2, mlp_b2, mout, nullptr, nullptr, nullptr, NTOK, 256, 256);

    final_ln_kernel<<<8192, 256, 0, stream>>>(sp, mout, ntw, ntb, out);
}

// Round 6
// 375.453 us; speedup vs baseline: 2.7972x; 1.0592x over previous
//
#include <hip/hip_runtime.h>
#include <math.h>

typedef unsigned short bf16_t;
typedef __attribute__((ext_vector_type(8))) short bf16x8;
typedef __attribute__((ext_vector_type(4))) float f32x4;

#define LSEQ 4096
#define NTOK 32768
#define HALF_TOK 16384
#define TPAD 72   // bf16 row stride for 64-col LDS tiles (144 B rows, 16B-aligned)

__device__ __forceinline__ float bf2f(bf16_t u) {
    unsigned int x = ((unsigned int)u) << 16;
    return __uint_as_float(x);
}
__device__ __forceinline__ bf16_t f2bf(float f) {
    unsigned int x = __float_as_uint(f);
    unsigned int r = (x + 0x7FFFu + ((x >> 16) & 1u)) >> 16;
    return (bf16_t)r;
}
__device__ __forceinline__ float siluf(float x) { return x / (1.f + __expf(-x)); }

__device__ __forceinline__ void unpack8(uint4 u, float* f) {
    f[0] = bf2f((bf16_t)(u.x & 0xffff)); f[1] = bf2f((bf16_t)(u.x >> 16));
    f[2] = bf2f((bf16_t)(u.y & 0xffff)); f[3] = bf2f((bf16_t)(u.y >> 16));
    f[4] = bf2f((bf16_t)(u.z & 0xffff)); f[5] = bf2f((bf16_t)(u.z >> 16));
    f[6] = bf2f((bf16_t)(u.w & 0xffff)); f[7] = bf2f((bf16_t)(u.w >> 16));
}
__device__ __forceinline__ uint4 pack8(const float* f) {
    uint4 u;
    u.x = (unsigned)f2bf(f[0]) | ((unsigned)f2bf(f[1]) << 16);
    u.y = (unsigned)f2bf(f[2]) | ((unsigned)f2bf(f[3]) << 16);
    u.z = (unsigned)f2bf(f[4]) | ((unsigned)f2bf(f[5]) << 16);
    u.w = (unsigned)f2bf(f[6]) | ((unsigned)f2bf(f[7]) << 16);
    return u;
}
__device__ __forceinline__ void st4(bf16_t* p, const float* o) {
    ushort4 u; u.x = f2bf(o[0]); u.y = f2bf(o[1]); u.z = f2bf(o[2]); u.w = f2bf(o[3]);
    *(ushort4*)p = u;
}

// async global->LDS, 16B per lane, dest = wave-uniform base + lane*16
__device__ __forceinline__ void gload16(const bf16_t* g, bf16_t* l) {
    __builtin_amdgcn_global_load_lds(
        (const __attribute__((address_space(1))) unsigned int*)g,
        (__attribute__((address_space(3))) unsigned int*)l,
        16, 0, 0);
}

// natural stage: T[r][c] = g[r*rs + c]  (64x64 bf16, vectorized)
__device__ __forceinline__ void stage_N(bf16_t (*T)[TPAD], const bf16_t* g, int rs, int tid) {
    #pragma unroll
    for (int it = 0; it < 2; ++it) {
        int slot = it * 256 + tid;
        int r = slot >> 3, co = slot & 7;
        *(uint4*)&T[r][co * 8] = *(const uint4*)(g + (size_t)r * rs + co * 8);
    }
}

// transposed stage: T[c][r] = g[r*rs + c]  (64x64 bf16, packed-pair b32 writes)
__device__ __forceinline__ void stage_T(bf16_t (*T)[TPAD], const bf16_t* g, int rs, int tid) {
    int rp = tid >> 3;               // 0..31 row-pair
    int co = tid & 7;                // col octet
    int r0 = rp * 2;
    const bf16_t* p0 = g + (size_t)r0 * rs + co * 8;
    uint4 a = *(const uint4*)p0;
    uint4 b = *(const uint4*)(p0 + rs);
    unsigned aa[4] = {a.x, a.y, a.z, a.w};
    unsigned bb[4] = {b.x, b.y, b.z, b.w};
    #pragma unroll
    for (int q = 0; q < 4; ++q) {
        int c0 = co * 8 + q * 2;
        *(unsigned*)&T[c0][r0]     = (aa[q] & 0xffffu) | (bb[q] << 16 & 0xffff0000u);
        *(unsigned*)&T[c0 + 1][r0] = (aa[q] >> 16)     | (bb[q] & 0xffff0000u);
    }
}

// ---------------- weight f32 -> bf16 ----------------
__global__ __launch_bounds__(256) void wconv_kernel(
    const float* __restrict__ s, bf16_t* __restrict__ d, int n4)
{
    int i = blockIdx.x * 256 + threadIdx.x;
    if (i < n4) {
        float4 v = ((const float4*)s)[i];
        ushort4 u; u.x = f2bf(v.x); u.y = f2bf(v.y); u.z = f2bf(v.z); u.w = f2bf(v.w);
        ((ushort4*)d)[i] = u;
    }
}

// ---------------- LayerNorm over concat(x0,x1) -> bf16 ----------------
__global__ __launch_bounds__(256) void ln_cat_kernel(
    const float* __restrict__ x0, const float* __restrict__ x1,
    const float* __restrict__ w, const float* __restrict__ b,
    bf16_t* __restrict__ out)
{
    int row = blockIdx.x * 4 + (threadIdx.x >> 6);
    int lane = threadIdx.x & 63;
    const float* src = (row < HALF_TOK) ? x0 + (size_t)row * 256
                                        : x1 + (size_t)(row - HALF_TOK) * 256;
    float4 v = ((const float4*)src)[lane];
    float s = v.x + v.y + v.z + v.w;
    float sq = v.x*v.x + v.y*v.y + v.z*v.z + v.w*v.w;
    #pragma unroll
    for (int off = 32; off; off >>= 1) { s += __shfl_xor(s, off); sq += __shfl_xor(sq, off); }
    float mu = s * (1.f/256.f);
    float var = sq * (1.f/256.f) - mu*mu;
    float inv = rsqrtf(var + 1e-5f);
    float4 wv = ((const float4*)w)[lane];
    float4 bv = ((const float4*)b)[lane];
    float o[4];
    o[0] = (v.x-mu)*inv*wv.x + bv.x;
    o[1] = (v.y-mu)*inv*wv.y + bv.y;
    o[2] = (v.z-mu)*inv*wv.z + bv.z;
    o[3] = (v.w-mu)*inv*wv.w + bv.w;
    st4(out + (size_t)row * 256 + lane * 4, o);
}

// ---------------- MFMA GEMM (m97 structure): C = A(MxK) @ W(NxK)^T ----------------
template<int AMODE, typename TC, bool BIAS, bool SILU, bool RES, bool DUAL>
__global__ __launch_bounds__(256) void gemm_mfma(
    const bf16_t* __restrict__ A, const bf16_t* __restrict__ W,
    const float* __restrict__ bias, TC* __restrict__ C,
    const float* __restrict__ r0, const float* __restrict__ r1,
    bf16_t* __restrict__ C2,
    int M, int N, int K)
{
    __shared__ bf16_t As[128 * 64];
    __shared__ bf16_t Ws[128 * 64];
    const int tid = threadIdx.x;
    const int wave = tid >> 6, lane = tid & 63;
    const int m0 = blockIdx.x << 7, n0 = blockIdx.y << 7;
    const int wr = wave >> 1, wc = wave & 1;
    const int fr = lane & 15, fk = lane >> 4;

    const int srow = lane >> 3;
    const int schunk = (lane & 7) ^ srow;

    f32x4 acc[4][4] = {};

    for (int k0 = 0; k0 < K; k0 += 64) {
        __syncthreads();
        #pragma unroll
        for (int t = 0; t < 4; ++t) {
            int row = wave * 32 + t * 8 + srow;
            const bf16_t* ga;
            if (AMODE == 0) {
                ga = A + (size_t)(m0 + row) * K + k0 + schunk * 8;
            } else {
                int m = m0 + row;
                if (k0 < 256) ga = A + (size_t)m * 256 + k0 + schunk * 8;
                else          ga = A + (size_t)(m ^ HALF_TOK) * 256 + (k0 - 256) + schunk * 8;
            }
            gload16(ga, As + wave * 2048 + t * 512);
            const bf16_t* gw = W + (size_t)(n0 + row) * K + k0 + schunk * 8;
            gload16(gw, Ws + wave * 2048 + t * 512);
        }
        __syncthreads();

        #pragma unroll
        for (int half = 0; half < 2; ++half) {
            bf16x8 af[4], bfr[4];
            #pragma unroll
            for (int i = 0; i < 4; ++i) {
                int row = wr * 64 + i * 16 + fr;
                int c16 = (half * 4 + fk) ^ (row & 7);
                af[i] = *(const bf16x8*)&As[row * 64 + c16 * 8];
            }
            #pragma unroll
            for (int j = 0; j < 4; ++j) {
                int row = wc * 64 + j * 16 + fr;
                int c16 = (half * 4 + fk) ^ (row & 7);
                bfr[j] = *(const bf16x8*)&Ws[row * 64 + c16 * 8];
            }
            #pragma unroll
            for (int i = 0; i < 4; ++i)
                #pragma unroll
                for (int j = 0; j < 4; ++j)
                    acc[i][j] = __builtin_amdgcn_mfma_f32_16x16x32_bf16(af[i], bfr[j], acc[i][j], 0, 0, 0);
        }
    }

    int fq = lane >> 4;
    #pragma unroll
    for (int j = 0; j < 4; ++j) {
        int n = n0 + wc * 64 + j * 16 + fr;
        if (n >= N) continue;
        float bval = BIAS ? bias[n] : 0.f;
        #pragma unroll
        for (int i = 0; i < 4; ++i) {
            #pragma unroll
            for (int q = 0; q < 4; ++q) {
                int m = m0 + wr * 64 + i * 16 + fq * 4 + q;
                float v = acc[i][j][q];
                if (BIAS) v += bval;
                if (SILU) v = siluf(v);
                if (RES) v += (m < HALF_TOK) ? r0[(size_t)m * 256 + n]
                                             : r1[(size_t)(m - HALF_TOK) * 256 + n];
                if (sizeof(TC) == 4) ((float*)C)[(size_t)m * N + n] = v;
                else ((bf16_t*)C)[(size_t)m * N + n] = f2bf(v);
                if (DUAL) C2[(size_t)m * N + n] = f2bf(v);
            }
        }
    }
}

// ---------------- mlp2 + final LN fused: out = LN(sp + hbuf@W2^T + b2) ----------------
// BM=128 tokens, BN=256 (full row -> LN in epilogue), K=256.
__global__ __launch_bounds__(256) void mlp2_ln_kernel(
    const bf16_t* __restrict__ A, const bf16_t* __restrict__ W,
    const float* __restrict__ bias, const float* __restrict__ sp,
    const float* __restrict__ lnw, const float* __restrict__ lnb,
    float* __restrict__ out)
{
    __shared__ bf16_t As[128 * 64];
    __shared__ bf16_t Ws[256 * 64];
    const int tid = threadIdx.x;
    const int wave = tid >> 6, lane = tid & 63;
    const int m0 = blockIdx.x << 7;
    const int fr = lane & 15, fk = lane >> 4;
    const int srow = lane >> 3;
    const int schunk = (lane & 7) ^ srow;

    f32x4 acc[2][16] = {};

    for (int k0 = 0; k0 < 256; k0 += 64) {
        __syncthreads();
        #pragma unroll
        for (int t = 0; t < 4; ++t) {
            int row = wave * 32 + t * 8 + srow;
            gload16(A + (size_t)(m0 + row) * 256 + k0 + schunk * 8, As + wave * 2048 + t * 512);
        }
        #pragma unroll
        for (int t = 0; t < 8; ++t) {
            int row = wave * 64 + t * 8 + srow;
            gload16(W + (size_t)row * 256 + k0 + schunk * 8, Ws + wave * 4096 + t * 512);
        }
        __syncthreads();

        #pragma unroll
        for (int half = 0; half < 2; ++half) {
            bf16x8 af[2];
            #pragma unroll
            for (int i = 0; i < 2; ++i) {
                int row = wave * 32 + i * 16 + fr;
                int c16 = (half * 4 + fk) ^ (row & 7);
                af[i] = *(const bf16x8*)&As[row * 64 + c16 * 8];
            }
            #pragma unroll
            for (int j = 0; j < 16; ++j) {
                int row = j * 16 + fr;
                int c16 = (half * 4 + fk) ^ (row & 7);
                bf16x8 bfr = *(const bf16x8*)&Ws[row * 64 + c16 * 8];
                acc[0][j] = __builtin_amdgcn_mfma_f32_16x16x32_bf16(af[0], bfr, acc[0][j], 0, 0, 0);
                acc[1][j] = __builtin_amdgcn_mfma_f32_16x16x32_bf16(af[1], bfr, acc[1][j], 0, 0, 0);
            }
        }
    }

    // epilogue: row m = m0 + wave*32 + i*16 + fk*4 + q ; col n = j*16 + fr
    float s1[2][4] = {}, s2[2][4] = {};
    #pragma unroll
    for (int i = 0; i < 2; ++i)
        #pragma unroll
        for (int j = 0; j < 16; ++j) {
            int n = j * 16 + fr;
            float bv = bias[n];
            #pragma unroll
            for (int q = 0; q < 4; ++q) {
                int m = m0 + wave * 32 + i * 16 + fk * 4 + q;
                float v = acc[i][j][q] + bv + sp[(size_t)m * 256 + n];
                acc[i][j][q] = v;
                s1[i][q] += v;
                s2[i][q] += v * v;
            }
        }
    #pragma unroll
    for (int i = 0; i < 2; ++i)
        #pragma unroll
        for (int q = 0; q < 4; ++q) {
            float a = s1[i][q], b2 = s2[i][q];
            #pragma unroll
            for (int off = 8; off; off >>= 1) {
                a  += __shfl_xor(a,  off);
                b2 += __shfl_xor(b2, off);
            }
            s1[i][q] = a * (1.f/256.f);                       // mu
            s2[i][q] = rsqrtf(b2 * (1.f/256.f) - s1[i][q]*s1[i][q] + 1e-5f);  // inv
        }
    #pragma unroll
    for (int i = 0; i < 2; ++i)
        #pragma unroll
        for (int j = 0; j < 16; ++j) {
            int n = j * 16 + fr;
            float wv = lnw[n], bv = lnb[n];
            #pragma unroll
            for (int q = 0; q < 4; ++q) {
                int m = m0 + wave * 32 + i * 16 + fk * 4 + q;
                out[(size_t)m * 256 + n] = (acc[i][j][q] - s1[i][q]) * s2[i][q] * wv + bv;
            }
        }
}

// ---------------- causal conv (width 4) + SiLU, sliding window: 4 tokens/thread ----------------
__global__ __launch_bounds__(320) void conv_dt_kernel(
    const bf16_t* __restrict__ zx, const float* __restrict__ cw,
    const float* __restrict__ cb, const float* __restrict__ dtb,
    const float* __restrict__ alog,
    bf16_t* __restrict__ conv_out, float* __restrict__ dts, float* __restrict__ lda)
{
    int tl = threadIdx.x / 80;            // token group 0..3
    int slot = threadIdx.x - tl * 80;     // channel slot 0..79
    int tok0 = blockIdx.x * 16 + tl * 4;  // 4 consecutive tokens
    int b = tok0 >> 12, t0 = tok0 & 4095;
    int ch = slot * 8;

    const bf16_t* basep = zx + (size_t)b * LSEQ * 1160 + 512 + ch;
    float f[7][8];
    #pragma unroll
    for (int i = 0; i < 7; ++i) {
        int tp = t0 - 3 + i;
        if (tp >= 0) {
            uint4 u = *(const uint4*)(basep + (size_t)tp * 1160);
            unpack8(u, f[i]);
        } else {
            #pragma unroll
            for (int j = 0; j < 8; ++j) f[i][j] = 0.f;
        }
    }
    float4 w4[8];
    float cbv[8];
    #pragma unroll
    for (int j = 0; j < 8; ++j) {
        w4[j] = *(const float4*)(cw + (ch + j) * 4);
        cbv[j] = cb[ch + j];
    }
    #pragma unroll
    for (int d = 0; d < 4; ++d) {
        float o[8];
        #pragma unroll
        for (int j = 0; j < 8; ++j) {
            float a = cbv[j] + w4[j].x * f[d][j] + w4[j].y * f[d+1][j]
                             + w4[j].z * f[d+2][j] + w4[j].w * f[d+3][j];
            o[j] = siluf(a);
        }
        *(uint4*)(conv_out + (size_t)(tok0 + d) * 640 + ch) = pack8(o);
    }

    if (slot < 8) {
        int h = slot;
        #pragma unroll
        for (int d = 0; d < 4; ++d) {
            int tok = tok0 + d;
            float raw = bf2f(zx[(size_t)tok * 1160 + 1152 + h]) + dtb[h];
            float dt = (raw > 20.f) ? raw : log1pf(__expf(raw));
            dts[tok * 8 + h] = dt;
            lda[tok * 8 + h] = -dt * __expf(alog[h]);
        }
    }
}

// ---------------- scan pass A (MFMA): S[p][n] = sum_s X[s][p]*wls[s] * B[s][n] ----------------
__global__ __launch_bounds__(256) void scan_passA(
    const bf16_t* __restrict__ conv_out, const float* __restrict__ dts,
    const float* __restrict__ lda, bf16_t* __restrict__ SH, float* __restrict__ Dtot)
{
    int bh = blockIdx.x, c = blockIdx.y;
    int b = bh >> 3, h = bh & 7;
    __shared__ bf16_t Xt[64][TPAD];
    __shared__ bf16_t Bw[64][TPAD];
    __shared__ float wls[64];
    int tid = threadIdx.x;
    int tokbase = b * LSEQ + c * 64;

    if (tid < 64) {
        float la = lda[(tokbase + tid) * 8 + h];
        #pragma unroll
        for (int off = 1; off < 64; off <<= 1) {
            float up = __shfl_up(la, off);
            if (tid >= off) la += up;
        }
        float tot = __shfl(la, 63);
        wls[tid] = __expf(tot - la) * dts[(tokbase + tid) * 8 + h];
        if (tid == 63) Dtot[bh * 64 + c] = __expf(tot);
    }
    stage_T(Xt, conv_out + (size_t)tokbase * 640 + h * 64, 640, tid);
    __syncthreads();

    {
        int rp = tid >> 3, co = tid & 7;
        int r0 = rp * 2;
        const bf16_t* p0 = conv_out + (size_t)(tokbase + r0) * 640 + 512 + co * 8;
        uint4 a = *(const uint4*)p0;
        uint4 bq = *(const uint4*)(p0 + 640);
        float fa[8], fb[8];
        unpack8(a, fa); unpack8(bq, fb);
        float w0 = wls[r0], w1 = wls[r0 + 1];
        #pragma unroll
        for (int q = 0; q < 8; ++q) {
            int c0 = co * 8 + q;
            *(unsigned*)&Bw[c0][r0] =
                (unsigned)f2bf(fa[q] * w0) | ((unsigned)f2bf(fb[q] * w1) << 16);
        }
    }
    __syncthreads();

    int wv = tid >> 6, lane = tid & 63;
    int fr = lane & 15, fk = lane >> 4;
    f32x4 acc[4] = {};
    bf16x8 af0 = *(const bf16x8*)&Xt[wv * 16 + fr][fk * 8];
    bf16x8 af1 = *(const bf16x8*)&Xt[wv * 16 + fr][32 + fk * 8];
    #pragma unroll
    for (int j = 0; j < 4; ++j) {
        bf16x8 b0 = *(const bf16x8*)&Bw[j * 16 + fr][fk * 8];
        bf16x8 b1 = *(const bf16x8*)&Bw[j * 16 + fr][32 + fk * 8];
        acc[j] = __builtin_amdgcn_mfma_f32_16x16x32_bf16(af0, b0, acc[j], 0, 0, 0);
        acc[j] = __builtin_amdgcn_mfma_f32_16x16x32_bf16(af1, b1, acc[j], 0, 0, 0);
    }
    __syncthreads();
    #pragma unroll
    for (int j = 0; j < 4; ++j)
        #pragma unroll
        for (int q = 0; q < 4; ++q) {
            int p = wv * 16 + fk * 4 + q;
            Xt[p][j * 16 + fr] = f2bf(acc[j][q]);
        }
    __syncthreads();
    size_t base = (size_t)(bh * 64 + c) * 4096;
    #pragma unroll
    for (int it = 0; it < 2; ++it) {
        int slot = it * 256 + tid;
        int p = slot >> 3, co = slot & 7;
        *(uint4*)(SH + base + p * 64 + co * 8) = *(const uint4*)&Xt[p][co * 8];
    }
}

// ---------------- scan pass B: inter-chunk recurrence ----------------
__global__ __launch_bounds__(256) void scan_passB(bf16_t* __restrict__ SH, const float* __restrict__ Dtot)
{
    int bh = blockIdx.x;
    int elem = blockIdx.y * 256 + threadIdx.x;
    size_t base = (size_t)bh * 64 * 4096 + elem;
    float H = 0.f;
    for (int c = 0; c < 64; ++c) {
        float d = Dtot[bh * 64 + c];
        size_t a = base + (size_t)c * 4096;
        float s = bf2f(SH[a]);
        SH[a] = f2bf(H);
        H = d * H + s;
    }
}

// ---------------- scan pass C (MFMA) ----------------
__global__ __launch_bounds__(256) void scan_passC(
    const bf16_t* __restrict__ conv_out, const float* __restrict__ dts,
    const float* __restrict__ lda, const bf16_t* __restrict__ SH,
    bf16_t* __restrict__ ybuf)
{
    int bh = blockIdx.x, c = blockIdx.y;
    int b = bh >> 3, h = bh & 7;
    __shared__ bf16_t Cs[64][TPAD];
    __shared__ bf16_t Bs[64][TPAD];
    __shared__ bf16_t Hs[64][TPAD];
    __shared__ bf16_t Xt[64][TPAD];
    __shared__ float La_sh[64], dt_sh[64], ce_sh[64];
    int tid = threadIdx.x;
    int tokbase = b * LSEQ + c * 64;
    size_t shbase = (size_t)(bh * 64 + c) * 4096;

    if (tid < 64) {
        float la = lda[(tokbase + tid) * 8 + h];
        #pragma unroll
        for (int off = 1; off < 64; off <<= 1) {
            float up = __shfl_up(la, off);
            if (tid >= off) la += up;
        }
        La_sh[tid] = la;
        ce_sh[tid] = __expf(la);
        dt_sh[tid] = dts[(tokbase + tid) * 8 + h];
    }
    stage_N(Cs, conv_out + (size_t)tokbase * 640 + 576, 640, tid);
    stage_N(Bs, conv_out + (size_t)tokbase * 640 + 512, 640, tid);
    stage_N(Hs, SH + shbase, 64, tid);
    stage_T(Xt, conv_out + (size_t)tokbase * 640 + h * 64, 640, tid);
    __syncthreads();

    int wv = tid >> 6, lane = tid & 63;
    int fr = lane & 15, fk = lane >> 4;
    int ws = wv * 16;

    bf16x8 afC0 = *(const bf16x8*)&Cs[ws + fr][fk * 8];
    bf16x8 afC1 = *(const bf16x8*)&Cs[ws + fr][32 + fk * 8];
    f32x4 accG[4] = {}, accH[4] = {};
    #pragma unroll
    for (int j = 0; j < 4; ++j) {
        bf16x8 b0 = *(const bf16x8*)&Bs[j * 16 + fr][fk * 8];
        bf16x8 b1 = *(const bf16x8*)&Bs[j * 16 + fr][32 + fk * 8];
        accG[j] = __builtin_amdgcn_mfma_f32_16x16x32_bf16(afC0, b0, accG[j], 0, 0, 0);
        accG[j] = __builtin_amdgcn_mfma_f32_16x16x32_bf16(afC1, b1, accG[j], 0, 0, 0);
        bf16x8 h0 = *(const bf16x8*)&Hs[j * 16 + fr][fk * 8];
        bf16x8 h1 = *(const bf16x8*)&Hs[j * 16 + fr][32 + fk * 8];
        accH[j] = __builtin_amdgcn_mfma_f32_16x16x32_bf16(afC0, h0, accH[j], 0, 0, 0);
        accH[j] = __builtin_amdgcn_mfma_f32_16x16x32_bf16(afC1, h1, accH[j], 0, 0, 0);
    }

    #pragma unroll
    for (int j = 0; j < 4; ++j)
        #pragma unroll
        for (int q = 0; q < 4; ++q) {
            int s = ws + fk * 4 + q;
            int r = j * 16 + fr;
            float m1 = 0.f;
            if (r <= s) m1 = accG[j][q] * __expf(La_sh[s] - La_sh[r]) * dt_sh[r];
            Cs[s][r] = f2bf(m1);
        }
    #pragma unroll
    for (int j = 0; j < 4; ++j)
        #pragma unroll
        for (int q = 0; q < 4; ++q)
            accH[j][q] *= ce_sh[ws + fk * 4 + q];

    bf16x8 afM0 = *(const bf16x8*)&Cs[ws + fr][fk * 8];
    bf16x8 afM1 = *(const bf16x8*)&Cs[ws + fr][32 + fk * 8];
    #pragma unroll
    for (int j = 0; j < 4; ++j) {
        bf16x8 x0 = *(const bf16x8*)&Xt[j * 16 + fr][fk * 8];
        bf16x8 x1 = *(const bf16x8*)&Xt[j * 16 + fr][32 + fk * 8];
        accH[j] = __builtin_amdgcn_mfma_f32_16x16x32_bf16(afM0, x0, accH[j], 0, 0, 0);
        accH[j] = __builtin_amdgcn_mfma_f32_16x16x32_bf16(afM1, x1, accH[j], 0, 0, 0);
    }

    __syncthreads();
    #pragma unroll
    for (int j = 0; j < 4; ++j)
        #pragma unroll
        for (int q = 0; q < 4; ++q) {
            int s = ws + fk * 4 + q;
            Bs[s][j * 16 + fr] = f2bf(accH[j][q]);
        }
    __syncthreads();
    #pragma unroll
    for (int it = 0; it < 2; ++it) {
        int slot = it * 256 + tid;
        int r = slot >> 3, co = slot & 7;
        *(uint4*)(ybuf + (size_t)(tokbase + r) * 512 + h * 64 + co * 8) = *(const uint4*)&Bs[r][co * 8];
    }
}

// ---------------- gate + RMSNorm, in-place on ybuf ----------------
__global__ __launch_bounds__(256) void gate_rms_kernel(
    bf16_t* __restrict__ y, const bf16_t* __restrict__ conv_out,
    const bf16_t* __restrict__ zx, const float* __restrict__ Dp,
    const float* __restrict__ rw)
{
    int row = blockIdx.x * 4 + (threadIdx.x >> 6);
    int lane = threadIdx.x & 63;
    uint4* yrow = (uint4*)(y + (size_t)row * 512);
    uint4 uy = yrow[lane];
    uint4 ux = *(const uint4*)(conv_out + (size_t)row * 640 + lane * 8);
    uint4 uz = *(const uint4*)(zx + (size_t)row * 1160 + lane * 8);
    float fy[8], fx[8], fz[8];
    unpack8(uy, fy); unpack8(ux, fx); unpack8(uz, fz);
    float d = Dp[lane >> 3];
    float v[8];
    float sq = 0.f;
    #pragma unroll
    for (int i = 0; i < 8; ++i) {
        v[i] = (fy[i] + d * fx[i]) * siluf(fz[i]);
        sq += v[i] * v[i];
    }
    #pragma unroll
    for (int off = 32; off; off >>= 1) sq += __shfl_xor(sq, off);
    float r = rsqrtf(sq * (1.f/512.f) + 1e-5f);
    float4 w0 = *(const float4*)(rw + lane * 8);
    float4 w1 = *(const float4*)(rw + lane * 8 + 4);
    float o[8];
    o[0] = v[0]*r*w0.x; o[1] = v[1]*r*w0.y; o[2] = v[2]*r*w0.z; o[3] = v[3]*r*w0.w;
    o[4] = v[4]*r*w1.x; o[5] = v[5]*r*w1.y; o[6] = v[6]*r*w1.z; o[7] = v[7]*r*w1.w;
    yrow[lane] = pack8(o);
}

extern "C" void kernel_launch(void* const* d_in, const int* in_sizes, int n_in,
                              void* d_out, int out_size, void* d_ws, size_t ws_size,
                              hipStream_t stream) {
    (void)in_sizes; (void)n_in; (void)out_size; (void)ws_size;
    const float* x0      = (const float*)d_in[0];
    const float* x1      = (const float*)d_in[1];
    const float* nsw     = (const float*)d_in[2];
    const float* nsb     = (const float*)d_in[3];
    const float* W_in    = (const float*)d_in[4];
    const float* conv_w  = (const float*)d_in[5];
    const float* conv_b  = (const float*)d_in[6];
    const float* dt_bias = (const float*)d_in[7];
    const float* A_log   = (const float*)d_in[8];
    const float* D_param = (const float*)d_in[9];
    const float* rms_w   = (const float*)d_in[10];
    const float* W_out   = (const float*)d_in[11];
    const float* mlp_w1  = (const float*)d_in[12];
    const float* mlp_b1  = (const float*)d_in[13];
    const float* mlp_w2  = (const float*)d_in[14];
    const float* mlp_b2  = (const float*)d_in[15];
    const float* ntw     = (const float*)d_in[16];
    const float* ntb     = (const float*)d_in[17];
    float* out = (float*)d_out;

    // ---- workspace layout (bytes), total ~188.4 MB ----
    char* base = (char*)d_ws;
    bf16_t* zx = (bf16_t*)base;           // 32768x1160 bf16 [in_proj..gate]
    float*  sp = (float*)base;            // later: 32768x256 f32 [out_proj..mlp2_ln]
    char* pB = base + 76021760;
    bf16_t* convo = (bf16_t*)pB;          // 32768x640 bf16 [conv..gate]
    bf16_t* hbuf  = (bf16_t*)pB;          // later: 32768x256 bf16 [mlp1..mlp2_ln]
    char* pC = pB + 41943040;
    bf16_t* x_norm = (bf16_t*)pC;         // 32768x256 bf16 [ln..in_proj]
    bf16_t* SH     = (bf16_t*)pC;         // 64x64x4096 bf16 [passA..passC]
    bf16_t* spb    = (bf16_t*)pC;         // later: 32768x256 bf16 [out_proj..mlp1]
    char* pD = pC + 33554432;
    bf16_t* ybuf = (bf16_t*)pD;           // 32768x512 bf16 [passC..out_proj]
    char* pE = pD + 33554432;
    float* dts  = (float*)pE;
    float* lda  = dts + 262144;
    float* dtot = lda + 262144;
    bf16_t* Wb_in = (bf16_t*)(dtot + 4096);
    bf16_t* Wb_o  = Wb_in + 296960;
    bf16_t* Wb_1  = Wb_o + 131072;
    bf16_t* Wb_2  = Wb_1 + 131072;

    wconv_kernel<<<(74240 + 255) / 256, 256, 0, stream>>>(W_in,   Wb_in, 74240);
    wconv_kernel<<<(32768 + 255) / 256, 256, 0, stream>>>(W_out,  Wb_o,  32768);
    wconv_kernel<<<(32768 + 255) / 256, 256, 0, stream>>>(mlp_w1, Wb_1,  32768);
    wconv_kernel<<<(16384 + 255) / 256, 256, 0, stream>>>(mlp_w2, Wb_2,  16384);

    ln_cat_kernel<<<8192, 256, 0, stream>>>(x0, x1, nsw, nsb, x_norm);

    dim3 g_in(256, 10);
    gemm_mfma<0, bf16_t, false, false, false, false><<<g_in, 256, 0, stream>>>(
        x_norm, Wb_in, nullptr, zx, nullptr, nullptr, nullptr, NTOK, 1160, 256);

    conv_dt_kernel<<<2048, 320, 0, stream>>>(zx, conv_w, conv_b, dt_bias, A_log, convo, dts, lda);

    dim3 g_scan(64, 64);
    scan_passA<<<g_scan, 256, 0, stream>>>(convo, dts, lda, SH, dtot);
    dim3 g_pb(64, 16);
    scan_passB<<<g_pb, 256, 0, stream>>>(SH, dtot);
    scan_passC<<<g_scan, 256, 0, stream>>>(convo, dts, lda, SH, ybuf);

    gate_rms_kernel<<<8192, 256, 0, stream>>>(ybuf, convo, zx, D_param, rms_w);

    dim3 g_out(256, 2);
    gemm_mfma<0, float, false, false, true, true><<<g_out, 256, 0, stream>>>(
        ybuf, Wb_o, nullptr, sp, x0, x1, spb, NTOK, 256, 512);

    gemm_mfma<1, bf16_t, true, true, false, false><<<g_out, 256, 0, stream>>>(
        spb, Wb_1, mlp_b1, hbuf, nullptr, nullptr, nullptr, NTOK, 256, 512);

    // mlp2 + final LN fused
    mlp2_ln_kernel<<<256, 256, 0, stream>>>(hbuf, Wb_2, mlp_b2, sp, ntw, ntb, out);
}

// Round 9
// 354.159 us; speedup vs baseline: 2.9654x; 1.0601x over previous
//
#include <hip/hip_runtime.h>
#include <math.h>

typedef unsigned short bf16_t;
typedef __attribute__((ext_vector_type(8))) short bf16x8;
typedef __attribute__((ext_vector_type(4))) float f32x4;

#define LSEQ 4096
#define NTOK 32768
#define HALF_TOK 16384
#define TPAD 72   // bf16 row stride for 64-col LDS tiles (144 B rows, 16B-aligned)

__device__ __forceinline__ float bf2f(bf16_t u) {
    unsigned int x = ((unsigned int)u) << 16;
    return __uint_as_float(x);
}
__device__ __forceinline__ bf16_t f2bf(float f) {
    unsigned int x = __float_as_uint(f);
    unsigned int r = (x + 0x7FFFu + ((x >> 16) & 1u)) >> 16;
    return (bf16_t)r;
}
__device__ __forceinline__ float siluf(float x) { return x / (1.f + __expf(-x)); }

__device__ __forceinline__ void unpack8(uint4 u, float* f) {
    f[0] = bf2f((bf16_t)(u.x & 0xffff)); f[1] = bf2f((bf16_t)(u.x >> 16));
    f[2] = bf2f((bf16_t)(u.y & 0xffff)); f[3] = bf2f((bf16_t)(u.y >> 16));
    f[4] = bf2f((bf16_t)(u.z & 0xffff)); f[5] = bf2f((bf16_t)(u.z >> 16));
    f[6] = bf2f((bf16_t)(u.w & 0xffff)); f[7] = bf2f((bf16_t)(u.w >> 16));
}
__device__ __forceinline__ uint4 pack8(const float* f) {
    uint4 u;
    u.x = (unsigned)f2bf(f[0]) | ((unsigned)f2bf(f[1]) << 16);
    u.y = (unsigned)f2bf(f[2]) | ((unsigned)f2bf(f[3]) << 16);
    u.z = (unsigned)f2bf(f[4]) | ((unsigned)f2bf(f[5]) << 16);
    u.w = (unsigned)f2bf(f[6]) | ((unsigned)f2bf(f[7]) << 16);
    return u;
}
__device__ __forceinline__ void st4(bf16_t* p, const float* o) {
    ushort4 u; u.x = f2bf(o[0]); u.y = f2bf(o[1]); u.z = f2bf(o[2]); u.w = f2bf(o[3]);
    *(ushort4*)p = u;
}

// async global->LDS, 16B per lane, dest = wave-uniform base + lane*16
__device__ __forceinline__ void gload16(const bf16_t* g, bf16_t* l) {
    __builtin_amdgcn_global_load_lds(
        (const __attribute__((address_space(1))) unsigned int*)g,
        (__attribute__((address_space(3))) unsigned int*)l,
        16, 0, 0);
}

// natural stage: T[r][c] = g[r*rs + c]  (64x64 bf16, vectorized)
__device__ __forceinline__ void stage_N(bf16_t (*T)[TPAD], const bf16_t* g, int rs, int tid) {
    #pragma unroll
    for (int it = 0; it < 2; ++it) {
        int slot = it * 256 + tid;
        int r = slot >> 3, co = slot & 7;
        *(uint4*)&T[r][co * 8] = *(const uint4*)(g + (size_t)r * rs + co * 8);
    }
}

// transposed stage: T[c][r] = g[r*rs + c]  (64x64 bf16, packed-pair b32 writes)
__device__ __forceinline__ void stage_T(bf16_t (*T)[TPAD], const bf16_t* g, int rs, int tid) {
    int rp = tid >> 3;               // 0..31 row-pair
    int co = tid & 7;                // col octet
    int r0 = rp * 2;
    const bf16_t* p0 = g + (size_t)r0 * rs + co * 8;
    uint4 a = *(const uint4*)p0;
    uint4 b = *(const uint4*)(p0 + rs);
    unsigned aa[4] = {a.x, a.y, a.z, a.w};
    unsigned bb[4] = {b.x, b.y, b.z, b.w};
    #pragma unroll
    for (int q = 0; q < 4; ++q) {
        int c0 = co * 8 + q * 2;
        *(unsigned*)&T[c0][r0]     = (aa[q] & 0xffffu) | (bb[q] << 16 & 0xffff0000u);
        *(unsigned*)&T[c0 + 1][r0] = (aa[q] >> 16)     | (bb[q] & 0xffff0000u);
    }
}

// ---------------- weight f32 -> bf16 ----------------
__global__ __launch_bounds__(256) void wconv_kernel(
    const float* __restrict__ s, bf16_t* __restrict__ d, int n4)
{
    int i = blockIdx.x * 256 + threadIdx.x;
    if (i < n4) {
        float4 v = ((const float4*)s)[i];
        ushort4 u; u.x = f2bf(v.x); u.y = f2bf(v.y); u.z = f2bf(v.z); u.w = f2bf(v.w);
        ((ushort4*)d)[i] = u;
    }
}

// ---------------- LayerNorm over concat(x0,x1) -> bf16 ----------------
__global__ __launch_bounds__(256) void ln_cat_kernel(
    const float* __restrict__ x0, const float* __restrict__ x1,
    const float* __restrict__ w, const float* __restrict__ b,
    bf16_t* __restrict__ out)
{
    int row = blockIdx.x * 4 + (threadIdx.x >> 6);
    int lane = threadIdx.x & 63;
    const float* src = (row < HALF_TOK) ? x0 + (size_t)row * 256
                                        : x1 + (size_t)(row - HALF_TOK) * 256;
    float4 v = ((const float4*)src)[lane];
    float s = v.x + v.y + v.z + v.w;
    float sq = v.x*v.x + v.y*v.y + v.z*v.z + v.w*v.w;
    #pragma unroll
    for (int off = 32; off; off >>= 1) { s += __shfl_xor(s, off); sq += __shfl_xor(sq, off); }
    float mu = s * (1.f/256.f);
    float var = sq * (1.f/256.f) - mu*mu;
    float inv = rsqrtf(var + 1e-5f);
    float4 wv = ((const float4*)w)[lane];
    float4 bv = ((const float4*)b)[lane];
    float o[4];
    o[0] = (v.x-mu)*inv*wv.x + bv.x;
    o[1] = (v.y-mu)*inv*wv.y + bv.y;
    o[2] = (v.z-mu)*inv*wv.z + bv.z;
    o[3] = (v.w-mu)*inv*wv.w + bv.w;
    st4(out + (size_t)row * 256 + lane * 4, o);
}

// ---------------- MFMA GEMM BM=128 (m97 structure): C = A(MxK) @ W(NxK)^T ----------------
template<int AMODE, typename TC, bool BIAS, bool SILU, bool RES, bool DUAL>
__global__ __launch_bounds__(256) void gemm_mfma(
    const bf16_t* __restrict__ A, const bf16_t* __restrict__ W,
    const float* __restrict__ bias, TC* __restrict__ C,
    const float* __restrict__ r0, const float* __restrict__ r1,
    bf16_t* __restrict__ C2,
    int M, int N, int K)
{
    __shared__ bf16_t As[128 * 64];
    __shared__ bf16_t Ws[128 * 64];
    const int tid = threadIdx.x;
    const int wave = tid >> 6, lane = tid & 63;
    const int m0 = blockIdx.x << 7, n0 = blockIdx.y << 7;
    const int wr = wave >> 1, wc = wave & 1;
    const int fr = lane & 15, fk = lane >> 4;

    const int srow = lane >> 3;
    const int schunk = (lane & 7) ^ srow;

    f32x4 acc[4][4] = {};

    for (int k0 = 0; k0 < K; k0 += 64) {
        __syncthreads();
        #pragma unroll
        for (int t = 0; t < 4; ++t) {
            int row = wave * 32 + t * 8 + srow;
            const bf16_t* ga;
            if (AMODE == 0) {
                ga = A + (size_t)(m0 + row) * K + k0 + schunk * 8;
            } else {
                int m = m0 + row;
                if (k0 < 256) ga = A + (size_t)m * 256 + k0 + schunk * 8;
                else          ga = A + (size_t)(m ^ HALF_TOK) * 256 + (k0 - 256) + schunk * 8;
            }
            gload16(ga, As + wave * 2048 + t * 512);
            const bf16_t* gw = W + (size_t)(n0 + row) * K + k0 + schunk * 8;
            gload16(gw, Ws + wave * 2048 + t * 512);
        }
        __syncthreads();

        #pragma unroll
        for (int half = 0; half < 2; ++half) {
            bf16x8 af[4], bfr[4];
            #pragma unroll
            for (int i = 0; i < 4; ++i) {
                int row = wr * 64 + i * 16 + fr;
                int c16 = (half * 4 + fk) ^ (row & 7);
                af[i] = *(const bf16x8*)&As[row * 64 + c16 * 8];
            }
            #pragma unroll
            for (int j = 0; j < 4; ++j) {
                int row = wc * 64 + j * 16 + fr;
                int c16 = (half * 4 + fk) ^ (row & 7);
                bfr[j] = *(const bf16x8*)&Ws[row * 64 + c16 * 8];
            }
            #pragma unroll
            for (int i = 0; i < 4; ++i)
                #pragma unroll
                for (int j = 0; j < 4; ++j)
                    acc[i][j] = __builtin_amdgcn_mfma_f32_16x16x32_bf16(af[i], bfr[j], acc[i][j], 0, 0, 0);
        }
    }

    int fq = lane >> 4;
    #pragma unroll
    for (int j = 0; j < 4; ++j) {
        int n = n0 + wc * 64 + j * 16 + fr;
        if (n >= N) continue;
        float bval = BIAS ? bias[n] : 0.f;
        #pragma unroll
        for (int i = 0; i < 4; ++i) {
            #pragma unroll
            for (int q = 0; q < 4; ++q) {
                int m = m0 + wr * 64 + i * 16 + fq * 4 + q;
                float v = acc[i][j][q];
                if (BIAS) v += bval;
                if (SILU) v = siluf(v);
                if (RES) v += (m < HALF_TOK) ? r0[(size_t)m * 256 + n]
                                             : r1[(size_t)(m - HALF_TOK) * 256 + n];
                if (sizeof(TC) == 4) ((float*)C)[(size_t)m * N + n] = v;
                else ((bf16_t*)C)[(size_t)m * N + n] = f2bf(v);
                if (DUAL) C2[(size_t)m * N + n] = f2bf(v);
            }
        }
    }
}

// ---------------- MFMA GEMM BM=64: more blocks/CU for skinny-N shapes ----------------
// grid (M/64, N/128); 4 waves as 2x2 over (64 rows, 128 cols); LDS 24KB.
template<int AMODE, typename TC, bool BIAS, bool SILU, bool RES, bool DUAL>
__global__ __launch_bounds__(256) void gemm_mfma64(
    const bf16_t* __restrict__ A, const bf16_t* __restrict__ W,
    const float* __restrict__ bias, TC* __restrict__ C,
    const float* __restrict__ r0, const float* __restrict__ r1,
    bf16_t* __restrict__ C2,
    int M, int N, int K)
{
    __shared__ bf16_t As[64 * 64];
    __shared__ bf16_t Ws[128 * 64];
    const int tid = threadIdx.x;
    const int wave = tid >> 6, lane = tid & 63;
    const int m0 = blockIdx.x << 6, n0 = blockIdx.y << 7;
    const int wr = wave >> 1, wc = wave & 1;
    const int fr = lane & 15, fk = lane >> 4;

    const int srow = lane >> 3;
    const int schunk = (lane & 7) ^ srow;

    f32x4 acc[2][4] = {};

    for (int k0 = 0; k0 < K; k0 += 64) {
        __syncthreads();
        #pragma unroll
        for (int t = 0; t < 2; ++t) {
            int row = wave * 16 + t * 8 + srow;
            const bf16_t* ga;
            if (AMODE == 0) {
                ga = A + (size_t)(m0 + row) * K + k0 + schunk * 8;
            } else {
                int m = m0 + row;
                if (k0 < 256) ga = A + (size_t)m * 256 + k0 + schunk * 8;
                else          ga = A + (size_t)(m ^ HALF_TOK) * 256 + (k0 - 256) + schunk * 8;
            }
            gload16(ga, As + wave * 1024 + t * 512);
        }
        #pragma unroll
        for (int t = 0; t < 4; ++t) {
            int row = wave * 32 + t * 8 + srow;
            const bf16_t* gw = W + (size_t)(n0 + row) * K + k0 + schunk * 8;
            gload16(gw, Ws + wave * 2048 + t * 512);
        }
        __syncthreads();

        #pragma unroll
        for (int half = 0; half < 2; ++half) {
            bf16x8 af[2], bfr[4];
            #pragma unroll
            for (int i = 0; i < 2; ++i) {
                int row = wr * 32 + i * 16 + fr;
                int c16 = (half * 4 + fk) ^ (row & 7);
                af[i] = *(const bf16x8*)&As[row * 64 + c16 * 8];
            }
            #pragma unroll
            for (int j = 0; j < 4; ++j) {
                int row = wc * 64 + j * 16 + fr;
                int c16 = (half * 4 + fk) ^ (row & 7);
                bfr[j] = *(const bf16x8*)&Ws[row * 64 + c16 * 8];
            }
            #pragma unroll
            for (int i = 0; i < 2; ++i)
                #pragma unroll
                for (int j = 0; j < 4; ++j)
                    acc[i][j] = __builtin_amdgcn_mfma_f32_16x16x32_bf16(af[i], bfr[j], acc[i][j], 0, 0, 0);
        }
    }

    int fq = lane >> 4;
    #pragma unroll
    for (int j = 0; j < 4; ++j) {
        int n = n0 + wc * 64 + j * 16 + fr;
        if (n >= N) continue;
        float bval = BIAS ? bias[n] : 0.f;
        #pragma unroll
        for (int i = 0; i < 2; ++i) {
            #pragma unroll
            for (int q = 0; q < 4; ++q) {
                int m = m0 + wr * 32 + i * 16 + fq * 4 + q;
                float v = acc[i][j][q];
                if (BIAS) v += bval;
                if (SILU) v = siluf(v);
                if (RES) v += (m < HALF_TOK) ? r0[(size_t)m * 256 + n]
                                             : r1[(size_t)(m - HALF_TOK) * 256 + n];
                if (sizeof(TC) == 4) ((float*)C)[(size_t)m * N + n] = v;
                else ((bf16_t*)C)[(size_t)m * N + n] = f2bf(v);
                if (DUAL) C2[(size_t)m * N + n] = f2bf(v);
            }
        }
    }
}

// ---------------- mlp2 + final LN fused (BM=128, round-6 verbatim) ----------------
__global__ __launch_bounds__(256) void mlp2_ln_kernel(
    const bf16_t* __restrict__ A, const bf16_t* __restrict__ W,
    const float* __restrict__ bias, const float* __restrict__ sp,
    const float* __restrict__ lnw, const float* __restrict__ lnb,
    float* __restrict__ out)
{
    __shared__ bf16_t As[128 * 64];
    __shared__ bf16_t Ws[256 * 64];
    const int tid = threadIdx.x;
    const int wave = tid >> 6, lane = tid & 63;
    const int m0 = blockIdx.x << 7;
    const int fr = lane & 15, fk = lane >> 4;
    const int srow = lane >> 3;
    const int schunk = (lane & 7) ^ srow;

    f32x4 acc[2][16] = {};

    for (int k0 = 0; k0 < 256; k0 += 64) {
        __syncthreads();
        #pragma unroll
        for (int t = 0; t < 4; ++t) {
            int row = wave * 32 + t * 8 + srow;
            gload16(A + (size_t)(m0 + row) * 256 + k0 + schunk * 8, As + wave * 2048 + t * 512);
        }
        #pragma unroll
        for (int t = 0; t < 8; ++t) {
            int row = wave * 64 + t * 8 + srow;
            gload16(W + (size_t)row * 256 + k0 + schunk * 8, Ws + wave * 4096 + t * 512);
        }
        __syncthreads();

        #pragma unroll
        for (int half = 0; half < 2; ++half) {
            bf16x8 af[2];
            #pragma unroll
            for (int i = 0; i < 2; ++i) {
                int row = wave * 32 + i * 16 + fr;
                int c16 = (half * 4 + fk) ^ (row & 7);
                af[i] = *(const bf16x8*)&As[row * 64 + c16 * 8];
            }
            #pragma unroll
            for (int j = 0; j < 16; ++j) {
                int row = j * 16 + fr;
                int c16 = (half * 4 + fk) ^ (row & 7);
                bf16x8 bfr = *(const bf16x8*)&Ws[row * 64 + c16 * 8];
                acc[0][j] = __builtin_amdgcn_mfma_f32_16x16x32_bf16(af[0], bfr, acc[0][j], 0, 0, 0);
                acc[1][j] = __builtin_amdgcn_mfma_f32_16x16x32_bf16(af[1], bfr, acc[1][j], 0, 0, 0);
            }
        }
    }

    // epilogue: row m = m0 + wave*32 + i*16 + fk*4 + q ; col n = j*16 + fr
    float s1[2][4] = {}, s2[2][4] = {};
    #pragma unroll
    for (int i = 0; i < 2; ++i)
        #pragma unroll
        for (int j = 0; j < 16; ++j) {
            int n = j * 16 + fr;
            float bv = bias[n];
            #pragma unroll
            for (int q = 0; q < 4; ++q) {
                int m = m0 + wave * 32 + i * 16 + fk * 4 + q;
                float v = acc[i][j][q] + bv + sp[(size_t)m * 256 + n];
                acc[i][j][q] = v;
                s1[i][q] += v;
                s2[i][q] += v * v;
            }
        }
    #pragma unroll
    for (int i = 0; i < 2; ++i)
        #pragma unroll
        for (int q = 0; q < 4; ++q) {
            float a = s1[i][q], b2 = s2[i][q];
            #pragma unroll
            for (int off = 8; off; off >>= 1) {
                a  += __shfl_xor(a,  off);
                b2 += __shfl_xor(b2, off);
            }
            s1[i][q] = a * (1.f/256.f);                       // mu
            s2[i][q] = rsqrtf(b2 * (1.f/256.f) - s1[i][q]*s1[i][q] + 1e-5f);  // inv
        }
    #pragma unroll
    for (int i = 0; i < 2; ++i)
        #pragma unroll
        for (int j = 0; j < 16; ++j) {
            int n = j * 16 + fr;
            float wv = lnw[n], bv = lnb[n];
            #pragma unroll
            for (int q = 0; q < 4; ++q) {
                int m = m0 + wave * 32 + i * 16 + fk * 4 + q;
                out[(size_t)m * 256 + n] = (acc[i][j][q] - s1[i][q]) * s2[i][q] * wv + bv;
            }
        }
}

// ---------------- causal conv (width 4) + SiLU, sliding window: 4 tokens/thread ----------------
__global__ __launch_bounds__(320) void conv_dt_kernel(
    const bf16_t* __restrict__ zx, const float* __restrict__ cw,
    const float* __restrict__ cb, const float* __restrict__ dtb,
    const float* __restrict__ alog,
    bf16_t* __restrict__ conv_out, float* __restrict__ dts, float* __restrict__ lda)
{
    int tl = threadIdx.x / 80;            // token group 0..3
    int slot = threadIdx.x - tl * 80;     // channel slot 0..79
    int tok0 = blockIdx.x * 16 + tl * 4;  // 4 consecutive tokens
    int b = tok0 >> 12, t0 = tok0 & 4095;
    int ch = slot * 8;

    const bf16_t* basep = zx + (size_t)b * LSEQ * 1160 + 512 + ch;
    float f[7][8];
    #pragma unroll
    for (int i = 0; i < 7; ++i) {
        int tp = t0 - 3 + i;
        if (tp >= 0) {
            uint4 u = *(const uint4*)(basep + (size_t)tp * 1160);
            unpack8(u, f[i]);
        } else {
            #pragma unroll
            for (int j = 0; j < 8; ++j) f[i][j] = 0.f;
        }
    }
    float4 w4[8];
    float cbv[8];
    #pragma unroll
    for (int j = 0; j < 8; ++j) {
        w4[j] = *(const float4*)(cw + (ch + j) * 4);
        cbv[j] = cb[ch + j];
    }
    #pragma unroll
    for (int d = 0; d < 4; ++d) {
        float o[8];
        #pragma unroll
        for (int j = 0; j < 8; ++j) {
            float a = cbv[j] + w4[j].x * f[d][j] + w4[j].y * f[d+1][j]
                             + w4[j].z * f[d+2][j] + w4[j].w * f[d+3][j];
            o[j] = siluf(a);
        }
        *(uint4*)(conv_out + (size_t)(tok0 + d) * 640 + ch) = pack8(o);
    }

    if (slot < 8) {
        int h = slot;
        #pragma unroll
        for (int d = 0; d < 4; ++d) {
            int tok = tok0 + d;
            float raw = bf2f(zx[(size_t)tok * 1160 + 1152 + h]) + dtb[h];
            float dt = (raw > 20.f) ? raw : log1pf(__expf(raw));
            dts[tok * 8 + h] = dt;
            lda[tok * 8 + h] = -dt * __expf(alog[h]);
        }
    }
}

// ---------------- scan pass A (MFMA): S[p][n] = sum_s X[s][p]*wls[s] * B[s][n] ----------------
__global__ __launch_bounds__(256) void scan_passA(
    const bf16_t* __restrict__ conv_out, const float* __restrict__ dts,
    const float* __restrict__ lda, bf16_t* __restrict__ SH, float* __restrict__ Dtot)
{
    int bh = blockIdx.x, c = blockIdx.y;
    int b = bh >> 3, h = bh & 7;
    __shared__ bf16_t Xt[64][TPAD];
    __shared__ bf16_t Bw[64][TPAD];
    __shared__ float wls[64];
    int tid = threadIdx.x;
    int tokbase = b * LSEQ + c * 64;

    if (tid < 64) {
        float la = lda[(tokbase + tid) * 8 + h];
        #pragma unroll
        for (int off = 1; off < 64; off <<= 1) {
            float up = __shfl_up(la, off);
            if (tid >= off) la += up;
        }
        float tot = __shfl(la, 63);
        wls[tid] = __expf(tot - la) * dts[(tokbase + tid) * 8 + h];
        if (tid == 63) Dtot[bh * 64 + c] = __expf(tot);
    }
    stage_T(Xt, conv_out + (size_t)tokbase * 640 + h * 64, 640, tid);
    __syncthreads();

    {
        int rp = tid >> 3, co = tid & 7;
        int r0 = rp * 2;
        const bf16_t* p0 = conv_out + (size_t)(tokbase + r0) * 640 + 512 + co * 8;
        uint4 a = *(const uint4*)p0;
        uint4 bq = *(const uint4*)(p0 + 640);
        float fa[8], fb[8];
        unpack8(a, fa); unpack8(bq, fb);
        float w0 = wls[r0], w1 = wls[r0 + 1];
        #pragma unroll
        for (int q = 0; q < 8; ++q) {
            int c0 = co * 8 + q;
            *(unsigned*)&Bw[c0][r0] =
                (unsigned)f2bf(fa[q] * w0) | ((unsigned)f2bf(fb[q] * w1) << 16);
        }
    }
    __syncthreads();

    int wv = tid >> 6, lane = tid & 63;
    int fr = lane & 15, fk = lane >> 4;
    f32x4 acc[4] = {};
    bf16x8 af0 = *(const bf16x8*)&Xt[wv * 16 + fr][fk * 8];
    bf16x8 af1 = *(const bf16x8*)&Xt[wv * 16 + fr][32 + fk * 8];
    #pragma unroll
    for (int j = 0; j < 4; ++j) {
        bf16x8 b0 = *(const bf16x8*)&Bw[j * 16 + fr][fk * 8];
        bf16x8 b1 = *(const bf16x8*)&Bw[j * 16 + fr][32 + fk * 8];
        acc[j] = __builtin_amdgcn_mfma_f32_16x16x32_bf16(af0, b0, acc[j], 0, 0, 0);
        acc[j] = __builtin_amdgcn_mfma_f32_16x16x32_bf16(af1, b1, acc[j], 0, 0, 0);
    }
    __syncthreads();
    #pragma unroll
    for (int j = 0; j < 4; ++j)
        #pragma unroll
        for (int q = 0; q < 4; ++q) {
            int p = wv * 16 + fk * 4 + q;
            Xt[p][j * 16 + fr] = f2bf(acc[j][q]);
        }
    __syncthreads();
    size_t base = (size_t)(bh * 64 + c) * 4096;
    #pragma unroll
    for (int it = 0; it < 2; ++it) {
        int slot = it * 256 + tid;
        int p = slot >> 3, co = slot & 7;
        *(uint4*)(SH + base + p * 64 + co * 8) = *(const uint4*)&Xt[p][co * 8];
    }
}

// ---------------- scan pass B: inter-chunk recurrence ----------------
__global__ __launch_bounds__(256) void scan_passB(bf16_t* __restrict__ SH, const float* __restrict__ Dtot)
{
    int bh = blockIdx.x;
    int elem = blockIdx.y * 256 + threadIdx.x;
    size_t base = (size_t)bh * 64 * 4096 + elem;
    float H = 0.f;
    for (int c = 0; c < 64; ++c) {
        float d = Dtot[bh * 64 + c];
        size_t a = base + (size_t)c * 4096;
        float s = bf2f(SH[a]);
        SH[a] = f2bf(H);
        H = d * H + s;
    }
}

// ---------------- scan pass C (MFMA) ----------------
__global__ __launch_bounds__(256) void scan_passC(
    const bf16_t* __restrict__ conv_out, const float* __restrict__ dts,
    const float* __restrict__ lda, const bf16_t* __restrict__ SH,
    bf16_t* __restrict__ ybuf)
{
    int bh = blockIdx.x, c = blockIdx.y;
    int b = bh >> 3, h = bh & 7;
    __shared__ bf16_t Cs[64][TPAD];
    __shared__ bf16_t Bs[64][TPAD];
    __shared__ bf16_t Hs[64][TPAD];
    __shared__ bf16_t Xt[64][TPAD];
    __shared__ float La_sh[64], dt_sh[64], ce_sh[64];
    int tid = threadIdx.x;
    int tokbase = b * LSEQ + c * 64;
    size_t shbase = (size_t)(bh * 64 + c) * 4096;

    if (tid < 64) {
        float la = lda[(tokbase + tid) * 8 + h];
        #pragma unroll
        for (int off = 1; off < 64; off <<= 1) {
            float up = __shfl_up(la, off);
            if (tid >= off) la += up;
        }
        La_sh[tid] = la;
        ce_sh[tid] = __expf(la);
        dt_sh[tid] = dts[(tokbase + tid) * 8 + h];
    }
    stage_N(Cs, conv_out + (size_t)tokbase * 640 + 576, 640, tid);
    stage_N(Bs, conv_out + (size_t)tokbase * 640 + 512, 640, tid);
    stage_N(Hs, SH + shbase, 64, tid);
    stage_T(Xt, conv_out + (size_t)tokbase * 640 + h * 64, 640, tid);
    __syncthreads();

    int wv = tid >> 6, lane = tid & 63;
    int fr = lane & 15, fk = lane >> 4;
    int ws = wv * 16;

    bf16x8 afC0 = *(const bf16x8*)&Cs[ws + fr][fk * 8];
    bf16x8 afC1 = *(const bf16x8*)&Cs[ws + fr][32 + fk * 8];
    f32x4 accG[4] = {}, accH[4] = {};
    #pragma unroll
    for (int j = 0; j < 4; ++j) {
        bf16x8 b0 = *(const bf16x8*)&Bs[j * 16 + fr][fk * 8];
        bf16x8 b1 = *(const bf16x8*)&Bs[j * 16 + fr][32 + fk * 8];
        accG[j] = __builtin_amdgcn_mfma_f32_16x16x32_bf16(afC0, b0, accG[j], 0, 0, 0);
        accG[j] = __builtin_amdgcn_mfma_f32_16x16x32_bf16(afC1, b1, accG[j], 0, 0, 0);
        bf16x8 h0 = *(const bf16x8*)&Hs[j * 16 + fr][fk * 8];
        bf16x8 h1 = *(const bf16x8*)&Hs[j * 16 + fr][32 + fk * 8];
        accH[j] = __builtin_amdgcn_mfma_f32_16x16x32_bf16(afC0, h0, accH[j], 0, 0, 0);
        accH[j] = __builtin_amdgcn_mfma_f32_16x16x32_bf16(afC1, h1, accH[j], 0, 0, 0);
    }

    #pragma unroll
    for (int j = 0; j < 4; ++j)
        #pragma unroll
        for (int q = 0; q < 4; ++q) {
            int s = ws + fk * 4 + q;
            int r = j * 16 + fr;
            float m1 = 0.f;
            if (r <= s) m1 = accG[j][q] * __expf(La_sh[s] - La_sh[r]) * dt_sh[r];
            Cs[s][r] = f2bf(m1);
        }
    #pragma unroll
    for (int j = 0; j < 4; ++j)
        #pragma unroll
        for (int q = 0; q < 4; ++q)
            accH[j][q] *= ce_sh[ws + fk * 4 + q];

    bf16x8 afM0 = *(const bf16x8*)&Cs[ws + fr][fk * 8];
    bf16x8 afM1 = *(const bf16x8*)&Cs[ws + fr][32 + fk * 8];
    #pragma unroll
    for (int j = 0; j < 4; ++j) {
        bf16x8 x0 = *(const bf16x8*)&Xt[j * 16 + fr][fk * 8];
        bf16x8 x1 = *(const bf16x8*)&Xt[j * 16 + fr][32 + fk * 8];
        accH[j] = __builtin_amdgcn_mfma_f32_16x16x32_bf16(afM0, x0, accH[j], 0, 0, 0);
        accH[j] = __builtin_amdgcn_mfma_f32_16x16x32_bf16(afM1, x1, accH[j], 0, 0, 0);
    }

    __syncthreads();
    #pragma unroll
    for (int j = 0; j < 4; ++j)
        #pragma unroll
        for (int q = 0; q < 4; ++q) {
            int s = ws + fk * 4 + q;
            Bs[s][j * 16 + fr] = f2bf(accH[j][q]);
        }
    __syncthreads();
    #pragma unroll
    for (int it = 0; it < 2; ++it) {
        int slot = it * 256 + tid;
        int r = slot >> 3, co = slot & 7;
        *(uint4*)(ybuf + (size_t)(tokbase + r) * 512 + h * 64 + co * 8) = *(const uint4*)&Bs[r][co * 8];
    }
}

// ---------------- gate + RMSNorm, in-place on ybuf ----------------
__global__ __launch_bounds__(256) void gate_rms_kernel(
    bf16_t* __restrict__ y, const bf16_t* __restrict__ conv_out,
    const bf16_t* __restrict__ zx, const float* __restrict__ Dp,
    const float* __restrict__ rw)
{
    int row = blockIdx.x * 4 + (threadIdx.x >> 6);
    int lane = threadIdx.x & 63;
    uint4* yrow = (uint4*)(y + (size_t)row * 512);
    uint4 uy = yrow[lane];
    uint4 ux = *(const uint4*)(conv_out + (size_t)row * 640 + lane * 8);
    uint4 uz = *(const uint4*)(zx + (size_t)row * 1160 + lane * 8);
    float fy[8], fx[8], fz[8];
    unpack8(uy, fy); unpack8(ux, fx); unpack8(uz, fz);
    float d = Dp[lane >> 3];
    float v[8];
    float sq = 0.f;
    #pragma unroll
    for (int i = 0; i < 8; ++i) {
        v[i] = (fy[i] + d * fx[i]) * siluf(fz[i]);
        sq += v[i] * v[i];
    }
    #pragma unroll
    for (int off = 32; off; off >>= 1) sq += __shfl_xor(sq, off);
    float r = rsqrtf(sq * (1.f/512.f) + 1e-5f);
    float4 w0 = *(const float4*)(rw + lane * 8);
    float4 w1 = *(const float4*)(rw + lane * 8 + 4);
    float o[8];
    o[0] = v[0]*r*w0.x; o[1] = v[1]*r*w0.y; o[2] = v[2]*r*w0.z; o[3] = v[3]*r*w0.w;
    o[4] = v[4]*r*w1.x; o[5] = v[5]*r*w1.y; o[6] = v[6]*r*w1.z; o[7] = v[7]*r*w1.w;
    yrow[lane] = pack8(o);
}

extern "C" void kernel_launch(void* const* d_in, const int* in_sizes, int n_in,
                              void* d_out, int out_size, void* d_ws, size_t ws_size,
                              hipStream_t stream) {
    (void)in_sizes; (void)n_in; (void)out_size; (void)ws_size;
    const float* x0      = (const float*)d_in[0];
    const float* x1      = (const float*)d_in[1];
    const float* nsw     = (const float*)d_in[2];
    const float* nsb     = (const float*)d_in[3];
    const float* W_in    = (const float*)d_in[4];
    const float* conv_w  = (const float*)d_in[5];
    const float* conv_b  = (const float*)d_in[6];
    const float* dt_bias = (const float*)d_in[7];
    const float* A_log   = (const float*)d_in[8];
    const float* D_param = (const float*)d_in[9];
    const float* rms_w   = (const float*)d_in[10];
    const float* W_out   = (const float*)d_in[11];
    const float* mlp_w1  = (const float*)d_in[12];
    const float* mlp_b1  = (const float*)d_in[13];
    const float* mlp_w2  = (const float*)d_in[14];
    const float* mlp_b2  = (const float*)d_in[15];
    const float* ntw     = (const float*)d_in[16];
    const float* ntb     = (const float*)d_in[17];
    float* out = (float*)d_out;

    // ---- workspace layout (bytes), total ~188.4 MB ----
    char* base = (char*)d_ws;
    bf16_t* zx = (bf16_t*)base;           // 32768x1160 bf16 [in_proj..gate]
    float*  sp = (float*)base;            // later: 32768x256 f32 [out_proj..mlp2_ln]
    char* pB = base + 76021760;
    bf16_t* convo = (bf16_t*)pB;          // 32768x640 bf16 [conv..gate]
    bf16_t* hbuf  = (bf16_t*)pB;          // later: 32768x256 bf16 [mlp1..mlp2_ln]
    char* pC = pB + 41943040;
    bf16_t* x_norm = (bf16_t*)pC;         // 32768x256 bf16 [ln..in_proj]
    bf16_t* SH     = (bf16_t*)pC;         // 64x64x4096 bf16 [passA..passC]
    bf16_t* spb    = (bf16_t*)pC;         // later: 32768x256 bf16 [out_proj..mlp1]
    char* pD = pC + 33554432;
    bf16_t* ybuf = (bf16_t*)pD;           // 32768x512 bf16 [passC..out_proj]
    char* pE = pD + 33554432;
    float* dts  = (float*)pE;
    float* lda  = dts + 262144;
    float* dtot = lda + 262144;
    bf16_t* Wb_in = (bf16_t*)(dtot + 4096);
    bf16_t* Wb_o  = Wb_in + 296960;
    bf16_t* Wb_1  = Wb_o + 131072;
    bf16_t* Wb_2  = Wb_1 + 131072;

    wconv_kernel<<<(74240 + 255) / 256, 256, 0, stream>>>(W_in,   Wb_in, 74240);
    wconv_kernel<<<(32768 + 255) / 256, 256, 0, stream>>>(W_out,  Wb_o,  32768);
    wconv_kernel<<<(32768 + 255) / 256, 256, 0, stream>>>(mlp_w1, Wb_1,  32768);
    wconv_kernel<<<(16384 + 255) / 256, 256, 0, stream>>>(mlp_w2, Wb_2,  16384);

    ln_cat_kernel<<<8192, 256, 0, stream>>>(x0, x1, nsw, nsb, x_norm);

    // in_proj: (32768x256)@(1160x256)^T -> zx bf16 ; 2560 blocks (10/CU)
    dim3 g_in(256, 10);
    gemm_mfma<0, bf16_t, false, false, false, false><<<g_in, 256, 0, stream>>>(
        x_norm, Wb_in, nullptr, zx, nullptr, nullptr, nullptr, NTOK, 1160, 256);

    conv_dt_kernel<<<2048, 320, 0, stream>>>(zx, conv_w, conv_b, dt_bias, A_log, convo, dts, lda);

    dim3 g_scan(64, 64);
    scan_passA<<<g_scan, 256, 0, stream>>>(convo, dts, lda, SH, dtot);
    dim3 g_pb(64, 16);
    scan_passB<<<g_pb, 256, 0, stream>>>(SH, dtot);
    scan_passC<<<g_scan, 256, 0, stream>>>(convo, dts, lda, SH, ybuf);

    gate_rms_kernel<<<8192, 256, 0, stream>>>(ybuf, convo, zx, D_param, rms_w);

    // out_proj + residual: (32768x512)@(256x512)^T + x_cat -> sp f32, spb bf16 ; BM=64, 1024 blocks
    dim3 g_out64(512, 2);
    gemm_mfma64<0, float, false, false, true, true><<<g_out64, 256, 0, stream>>>(
        ybuf, Wb_o, nullptr, sp, x0, x1, spb, NTOK, 256, 512);

    // mlp1: concat(spb[m], spb[m^HALF]) @ (256x512)^T + b1, SiLU -> hbuf bf16 ; BM=64
    gemm_mfma64<1, bf16_t, true, true, false, false><<<g_out64, 256, 0, stream>>>(
        spb, Wb_1, mlp_b1, hbuf, nullptr, nullptr, nullptr, NTOK, 256, 512);

    // mlp2 + final LN fused ; BM=128 (round-6 verbatim), 256 blocks
    mlp2_ln_kernel<<<256, 256, 0, stream>>>(hbuf, Wb_2, mlp_b2, sp, ntw, ntb, out);
}